// Round 1
// baseline (4500.268 us; speedup 1.0000x reference)
//
#include <hip/hip_runtime.h>
#include <math.h>

static constexpr int Bn  = 8;
static constexpr int Cn  = 512;
static constexpr int HWn = 1024;   // 32*32
static constexpr int Sn  = 1024;   // seq len
static constexpr int NCn = 77;
static constexpr int DCn = 768;

// ======================= GroupNorm: (B,C,H,W) -> (B,C,HW) normalized =======================
__global__ __launch_bounds__(256) void gn_kernel(const float* __restrict__ x,
    const float* __restrict__ gs, const float* __restrict__ gb, float* __restrict__ out)
{
  int b = blockIdx.x >> 5, g = blockIdx.x & 31;            // 32 groups, 16 ch each
  const float* xp = x + ((size_t)b * Cn + g * 16) * HWn;
  float s = 0.f, ss = 0.f;
  for (int e = threadIdx.x; e < 16 * HWn; e += 256) {
    float v = xp[e];
    s += v; ss += v * v;
  }
  __shared__ float red[10];
  #pragma unroll
  for (int o = 32; o; o >>= 1) { s += __shfl_xor(s, o, 64); ss += __shfl_xor(ss, o, 64); }
  if ((threadIdx.x & 63) == 0) { red[threadIdx.x >> 6] = s; red[(threadIdx.x >> 6) + 4] = ss; }
  __syncthreads();
  if (threadIdx.x == 0) {
    float st  = red[0] + red[1] + red[2] + red[3];
    float sst = red[4] + red[5] + red[6] + red[7];
    float mu  = st * (1.f / 16384.f);
    red[8] = mu;
    red[9] = rsqrtf(sst * (1.f / 16384.f) - mu * mu + 1e-6f);
  }
  __syncthreads();
  float mu = red[8], inv = red[9];
  float* op = out + ((size_t)b * Cn + g * 16) * HWn;
  for (int e = threadIdx.x; e < 16 * HWn; e += 256) {
    int cl = e >> 10;
    op[e] = (xp[e] - mu) * inv * gs[g * 16 + cl] + gb[g * 16 + cl];
  }
}

// ======================= LayerNorm over last dim 512; 1 wave per row =======================
__global__ __launch_bounds__(256) void ln_kernel(const float* __restrict__ in,
    const float* __restrict__ s, const float* __restrict__ b, float* __restrict__ out)
{
  int row  = blockIdx.x * 4 + (threadIdx.x >> 6);
  int lane = threadIdx.x & 63;
  const float* ip = in + (size_t)row * Cn + lane * 8;
  float4 v0 = *(const float4*)ip;
  float4 v1 = *(const float4*)(ip + 4);
  float sum = v0.x + v0.y + v0.z + v0.w + v1.x + v1.y + v1.z + v1.w;
  float ss  = v0.x*v0.x + v0.y*v0.y + v0.z*v0.z + v0.w*v0.w
            + v1.x*v1.x + v1.y*v1.y + v1.z*v1.z + v1.w*v1.w;
  #pragma unroll
  for (int o = 32; o; o >>= 1) { sum += __shfl_xor(sum, o, 64); ss += __shfl_xor(ss, o, 64); }
  float mu  = sum * (1.f / Cn);
  float inv = rsqrtf(ss * (1.f / Cn) - mu * mu + 1e-5f);
  const float4 s0 = *(const float4*)(s + lane * 8);
  const float4 s1 = *(const float4*)(s + lane * 8 + 4);
  const float4 b0 = *(const float4*)(b + lane * 8);
  const float4 b1 = *(const float4*)(b + lane * 8 + 4);
  float4 o0, o1;
  o0.x = (v0.x - mu) * inv * s0.x + b0.x;
  o0.y = (v0.y - mu) * inv * s0.y + b0.y;
  o0.z = (v0.z - mu) * inv * s0.z + b0.z;
  o0.w = (v0.w - mu) * inv * s0.w + b0.w;
  o1.x = (v1.x - mu) * inv * s1.x + b1.x;
  o1.y = (v1.y - mu) * inv * s1.y + b1.y;
  o1.z = (v1.z - mu) * inv * s1.z + b1.z;
  o1.w = (v1.w - mu) * inv * s1.w + b1.w;
  float* op = out + (size_t)row * Cn + lane * 8;
  *(float4*)op       = o0;
  *(float4*)(op + 4) = o1;
}

// ======================= Generic GEMM: out = A @ W (+bias)(+res) ===========================
// 64x64 tile, BK=16, 256 threads, 4x4 per thread.
// AL=0: A row-major MxK.  AL=1: A in pixel layout (b, k, p) with m = b*HWn + p.
// EPI=0 none, 1 +bias[n], 2 +bias[n]+res[m*N+n].
template<int AL, int EPI>
__global__ __launch_bounds__(256) void gemm64(const float* __restrict__ A,
    const float* __restrict__ W, const float* __restrict__ bias,
    const float* __restrict__ res, float* __restrict__ out, int M, int K, int N)
{
  __shared__ float As[16][68];
  __shared__ float Ws[16][68];
  int tid = threadIdx.x;
  int n0 = blockIdx.x * 64;
  int m0 = blockIdx.y * 64;
  int tx = tid & 15, ty = tid >> 4;
  float acc[4][4] = {};
  for (int k0 = 0; k0 < K; k0 += 16) {
    if (AL == 0) {
      int kl = tid & 15, ml = tid >> 4;
      #pragma unroll
      for (int p = 0; p < 4; p++) {
        int m = m0 + ml + p * 16;
        float v = 0.f;
        if (m < M) v = A[(size_t)m * K + k0 + kl];
        As[kl][ml + p * 16] = v;
      }
    } else {
      int pl = tid & 63, kl0 = tid >> 6;
      int m = m0 + pl;                 // M multiple of 64 guaranteed here
      int bb = m >> 10, pp = m & 1023;
      #pragma unroll
      for (int p = 0; p < 4; p++) {
        int kk = k0 + kl0 + p * 4;
        As[kl0 + p * 4][pl] = A[((size_t)bb * K + kk) * HWn + pp];
      }
    }
    {
      int nl = tid & 63, kl0 = tid >> 6;
      #pragma unroll
      for (int p = 0; p < 4; p++)
        Ws[kl0 + p * 4][nl] = W[(size_t)(k0 + kl0 + p * 4) * N + n0 + nl];
    }
    __syncthreads();
    #pragma unroll
    for (int kk = 0; kk < 16; kk++) {
      const float4 a4 = *(const float4*)&As[kk][ty * 4];
      const float4 b4 = *(const float4*)&Ws[kk][tx * 4];
      float av[4] = {a4.x, a4.y, a4.z, a4.w};
      float bv[4] = {b4.x, b4.y, b4.z, b4.w};
      #pragma unroll
      for (int i = 0; i < 4; i++)
        #pragma unroll
        for (int j = 0; j < 4; j++)
          acc[i][j] += av[i] * bv[j];
    }
    __syncthreads();
  }
  #pragma unroll
  for (int i = 0; i < 4; i++) {
    int m = m0 + ty * 4 + i;
    if (m < M) {
      float4 o4 = make_float4(acc[i][0], acc[i][1], acc[i][2], acc[i][3]);
      if (EPI >= 1) {
        o4.x += bias[n0 + tx * 4 + 0];
        o4.y += bias[n0 + tx * 4 + 1];
        o4.z += bias[n0 + tx * 4 + 2];
        o4.w += bias[n0 + tx * 4 + 3];
      }
      if (EPI == 2) {
        const float4 r4 = *(const float4*)(res + (size_t)m * N + n0 + tx * 4);
        o4.x += r4.x; o4.y += r4.y; o4.z += r4.z; o4.w += r4.w;
      }
      *(float4*)(out + (size_t)m * N + n0 + tx * 4) = o4;
    }
  }
}

// ======================= Fused GEGLU GEMM: out = u * gelu(g) ================================
// W is (K, 4096); u-cols j, gate-cols j+2048. out is (M, 2048).
__global__ __launch_bounds__(256) void ff_gate(const float* __restrict__ A,
    const float* __restrict__ W, const float* __restrict__ bias,
    float* __restrict__ out, int M, int K)
{
  __shared__ float As[16][68];
  __shared__ float Wu[16][68];
  __shared__ float Wg[16][68];
  int tid = threadIdx.x;
  int n0 = blockIdx.x * 64;
  int m0 = blockIdx.y * 64;
  int tx = tid & 15, ty = tid >> 4;
  float au[4][4] = {}, ag[4][4] = {};
  for (int k0 = 0; k0 < K; k0 += 16) {
    {
      int kl = tid & 15, ml = tid >> 4;
      #pragma unroll
      for (int p = 0; p < 4; p++)
        As[kl][ml + p * 16] = A[(size_t)(m0 + ml + p * 16) * K + k0 + kl];
    }
    {
      int nl = tid & 63, kl0 = tid >> 6;
      #pragma unroll
      for (int p = 0; p < 4; p++) {
        const float* wr = W + (size_t)(k0 + kl0 + p * 4) * 4096;
        Wu[kl0 + p * 4][nl] = wr[n0 + nl];
        Wg[kl0 + p * 4][nl] = wr[2048 + n0 + nl];
      }
    }
    __syncthreads();
    #pragma unroll
    for (int kk = 0; kk < 16; kk++) {
      const float4 a4  = *(const float4*)&As[kk][ty * 4];
      const float4 u4  = *(const float4*)&Wu[kk][tx * 4];
      const float4 g4  = *(const float4*)&Wg[kk][tx * 4];
      float av[4] = {a4.x, a4.y, a4.z, a4.w};
      float uv[4] = {u4.x, u4.y, u4.z, u4.w};
      float gv[4] = {g4.x, g4.y, g4.z, g4.w};
      #pragma unroll
      for (int i = 0; i < 4; i++)
        #pragma unroll
        for (int j = 0; j < 4; j++) {
          au[i][j] += av[i] * uv[j];
          ag[i][j] += av[i] * gv[j];
        }
    }
    __syncthreads();
  }
  #pragma unroll
  for (int i = 0; i < 4; i++) {
    int m = m0 + ty * 4 + i;
    float4 o4;
    #pragma unroll
    for (int j = 0; j < 4; j++) {
      float u = au[i][j] + bias[n0 + tx * 4 + j];
      float g = ag[i][j] + bias[2048 + n0 + tx * 4 + j];
      float ge = 0.5f * g * (1.f + erff(g * 0.70710678118f));
      ((float*)&o4)[j] = u * ge;
    }
    *(float4*)(out + (size_t)m * 2048 + n0 + tx * 4) = o4;
  }
}

// ======================= Self-attention (S=1024, DH=64, NO 1/sqrt(d) scale) ================
// grid: B*NH*(S/16) blocks; each block: 16 query rows for one (b, head).
__global__ __launch_bounds__(256) void attn_self(const float* __restrict__ q,
    const float* __restrict__ k, const float* __restrict__ v, float* __restrict__ o)
{
  int blk = blockIdx.x;
  int i0 = (blk & 63) << 4;
  int n  = (blk >> 6) & 7;
  int b  = blk >> 9;
  __shared__ float qs[16][64];
  __shared__ float sc[16][1024];
  __shared__ float invs[16];
  int tid = threadIdx.x;
  int d = tid & 63, rg = tid >> 6;
  const float* qbase = q + ((size_t)b * Sn + i0) * Cn + n * 64;
  for (int r = rg; r < 16; r += 4) qs[r][d] = qbase[(size_t)r * Cn + d];
  __syncthreads();
  // ---- scores: thread computes 16 rows x 4 keys (j0 = tid*4) ----
  const float* kb = k + (size_t)b * Sn * Cn + n * 64;
  {
    float acc[16][4];
    #pragma unroll
    for (int r = 0; r < 16; r++)
      #pragma unroll
      for (int j = 0; j < 4; j++) acc[r][j] = 0.f;
    int j0 = tid * 4;
    for (int d0 = 0; d0 < 64; d0 += 4) {
      float4 k4[4];
      #pragma unroll
      for (int jj = 0; jj < 4; jj++)
        k4[jj] = *(const float4*)(kb + (size_t)(j0 + jj) * Cn + d0);
      #pragma unroll
      for (int r = 0; r < 16; r++) {
        const float4 q4 = *(const float4*)&qs[r][d0];
        #pragma unroll
        for (int jj = 0; jj < 4; jj++)
          acc[r][jj] += q4.x * k4[jj].x + q4.y * k4[jj].y + q4.z * k4[jj].z + q4.w * k4[jj].w;
      }
    }
    #pragma unroll
    for (int r = 0; r < 16; r++)
      *(float4*)&sc[r][j0] = make_float4(acc[r][0], acc[r][1], acc[r][2], acc[r][3]);
  }
  __syncthreads();
  // ---- softmax: one wave per row (4 waves handle 16 rows) ----
  int lane = tid & 63, wid = tid >> 6;
  for (int r = wid; r < 16; r += 4) {
    float mx = -1e30f;
    for (int j = lane; j < 1024; j += 64) mx = fmaxf(mx, sc[r][j]);
    #pragma unroll
    for (int off = 32; off; off >>= 1) mx = fmaxf(mx, __shfl_xor(mx, off, 64));
    float sum = 0.f;
    for (int j = lane; j < 1024; j += 64) {
      float p = __expf(sc[r][j] - mx);
      sc[r][j] = p; sum += p;
    }
    #pragma unroll
    for (int off = 32; off; off >>= 1) sum += __shfl_xor(sum, off, 64);
    if (lane == 0) invs[r] = 1.f / sum;
  }
  __syncthreads();
  // ---- PV: thread owns dim d for 4 rows ----
  const float* vbp = v + (size_t)b * Sn * Cn + n * 64;
  float accv[4] = {0.f, 0.f, 0.f, 0.f};
  for (int j0 = 0; j0 < 1024; j0 += 4) {
    float vv[4];
    #pragma unroll
    for (int jj = 0; jj < 4; jj++) vv[jj] = vbp[(size_t)(j0 + jj) * Cn + d];
    #pragma unroll
    for (int ri = 0; ri < 4; ri++) {
      const float4 p4 = *(const float4*)&sc[rg * 4 + ri][j0];
      accv[ri] += p4.x * vv[0] + p4.y * vv[1] + p4.z * vv[2] + p4.w * vv[3];
    }
  }
  float* ob = o + ((size_t)b * Sn + i0) * Cn + n * 64;
  #pragma unroll
  for (int ri = 0; ri < 4; ri++)
    ob[(size_t)(rg * 4 + ri) * Cn + d] = accv[ri] * invs[rg * 4 + ri];
}

// ======================= Cross-attention (Sk=77) ===========================================
__global__ __launch_bounds__(256) void attn_cross(const float* __restrict__ q,
    const float* __restrict__ k, const float* __restrict__ v, float* __restrict__ o)
{
  int blk = blockIdx.x;
  int i0 = (blk & 63) << 4;
  int n  = (blk >> 6) & 7;
  int b  = blk >> 9;
  __shared__ float qs[16][64];
  __shared__ float sc[16][80];
  __shared__ float invs[16];
  int tid = threadIdx.x;
  int d = tid & 63, rg = tid >> 6;
  const float* qbase = q + ((size_t)b * Sn + i0) * Cn + n * 64;
  for (int r = rg; r < 16; r += 4) qs[r][d] = qbase[(size_t)r * Cn + d];
  __syncthreads();
  int r = tid >> 4, t16 = tid & 15;
  const float* kb = k + (size_t)b * NCn * Cn + n * 64;
  for (int j = t16; j < NCn; j += 16) {
    const float* kr = kb + (size_t)j * Cn;
    float acc = 0.f;
    #pragma unroll
    for (int d0 = 0; d0 < 64; d0 += 4) {
      const float4 k4 = *(const float4*)(kr + d0);
      const float4 q4 = *(const float4*)&qs[r][d0];
      acc += q4.x * k4.x + q4.y * k4.y + q4.z * k4.z + q4.w * k4.w;
    }
    sc[r][j] = acc;
  }
  __syncthreads();
  float mx = -1e30f;
  for (int j = t16; j < NCn; j += 16) mx = fmaxf(mx, sc[r][j]);
  #pragma unroll
  for (int off = 8; off; off >>= 1) mx = fmaxf(mx, __shfl_xor(mx, off, 64));
  float sum = 0.f;
  for (int j = t16; j < NCn; j += 16) {
    float p = __expf(sc[r][j] - mx);
    sc[r][j] = p; sum += p;
  }
  #pragma unroll
  for (int off = 8; off; off >>= 1) sum += __shfl_xor(sum, off, 64);
  if (t16 == 0) invs[r] = 1.f / sum;
  __syncthreads();
  const float* vbp = v + (size_t)b * NCn * Cn + n * 64;
  float accv[4] = {0.f, 0.f, 0.f, 0.f};
  for (int j = 0; j < NCn; j++) {
    float vv = vbp[(size_t)j * Cn + d];
    #pragma unroll
    for (int ri = 0; ri < 4; ri++) accv[ri] += sc[rg * 4 + ri][j] * vv;
  }
  float* ob = o + ((size_t)b * Sn + i0) * Cn + n * 64;
  #pragma unroll
  for (int ri = 0; ri < 4; ri++)
    ob[(size_t)(rg * 4 + ri) * Cn + d] = accv[ri] * invs[rg * 4 + ri];
}

// ======================= Transpose (B,HW,C)->(B,C,HW) + pout_b + x_in ======================
__global__ __launch_bounds__(256) void trans_add(const float* __restrict__ tin,
    const float* __restrict__ pb, const float* __restrict__ xin, float* __restrict__ out)
{
  __shared__ float tile[32][33];
  int p0 = blockIdx.x * 32, d0 = blockIdx.y * 32, b = blockIdx.z;
  int px = threadIdx.x & 31, py = threadIdx.x >> 5;
  for (int yy = py; yy < 32; yy += 8)
    tile[yy][px] = tin[((size_t)b * HWn + p0 + yy) * Cn + d0 + px];
  __syncthreads();
  for (int yy = py; yy < 32; yy += 8) {
    int dd = d0 + yy;
    size_t oidx = ((size_t)b * Cn + dd) * HWn + p0 + px;
    out[oidx] = tile[px][yy] + pb[dd] + xin[oidx];
  }
}

// ======================= Launch ============================================================
extern "C" void kernel_launch(void* const* d_in, const int* in_sizes, int n_in,
                              void* d_out, int out_size, void* d_ws, size_t ws_size,
                              hipStream_t stream) {
  const float* x      = (const float*)d_in[0];
  const float* cond   = (const float*)d_in[1];
  const float* gn_s   = (const float*)d_in[2];
  const float* gn_b   = (const float*)d_in[3];
  const float* pin_w  = (const float*)d_in[4];
  const float* pin_b  = (const float*)d_in[5];
  const float* pout_w = (const float*)d_in[6];
  const float* pout_b = (const float*)d_in[7];
  const float* ln1_s  = (const float*)d_in[8];
  const float* ln1_b  = (const float*)d_in[9];
  const float* sa_wq  = (const float*)d_in[10];
  const float* sa_wk  = (const float*)d_in[11];
  const float* sa_wv  = (const float*)d_in[12];
  const float* sa_wo  = (const float*)d_in[13];
  const float* sa_bo  = (const float*)d_in[14];
  const float* ln2_s  = (const float*)d_in[15];
  const float* ln2_b  = (const float*)d_in[16];
  const float* ca_wq  = (const float*)d_in[17];
  const float* ca_wk  = (const float*)d_in[18];
  const float* ca_wv  = (const float*)d_in[19];
  const float* ca_wo  = (const float*)d_in[20];
  const float* ca_bo  = (const float*)d_in[21];
  const float* ln3_s  = (const float*)d_in[22];
  const float* ln3_b  = (const float*)d_in[23];
  const float* ff_w1  = (const float*)d_in[24];
  const float* ff_b1  = (const float*)d_in[25];
  const float* ff_w2  = (const float*)d_in[26];
  const float* ff_b2  = (const float*)d_in[27];

  const int M = Bn * Sn;  // 8192
  float* ws = (float*)d_ws;
  float* t  = ws;                       // 4M floats
  float* qb = ws + (size_t)4  * 1024 * 1024;
  float* kb = ws + (size_t)8  * 1024 * 1024;
  float* vb = ws + (size_t)12 * 1024 * 1024;
  float* ao = ws + (size_t)16 * 1024 * 1024;
  float* g  = ws + (size_t)20 * 1024 * 1024;  // 16M floats (GEGLU / also GN scratch)
  float* a  = (float*)d_out;            // LN scratch aliases d_out (4M floats, rewritten at end)

  dim3 gemmGrid(8, 128);

  // GroupNorm -> g (B,C,HW layout), then proj_in (pixel-layout A) -> t (B,S,C)
  gn_kernel<<<256, 256, 0, stream>>>(x, gn_s, gn_b, g);
  gemm64<1, 1><<<gemmGrid, 256, 0, stream>>>(g, pin_w, pin_b, nullptr, t, M, Cn, Cn);

  for (int i = 0; i < 2; i++) {
    const size_t wCC = (size_t)i * Cn * Cn;
    const size_t wDC = (size_t)i * DCn * Cn;
    // --- self-attention ---
    ln_kernel<<<2048, 256, 0, stream>>>(t, ln1_s + i * Cn, ln1_b + i * Cn, a);
    gemm64<0, 0><<<gemmGrid, 256, 0, stream>>>(a, sa_wq + wCC, nullptr, nullptr, qb, M, Cn, Cn);
    gemm64<0, 0><<<gemmGrid, 256, 0, stream>>>(a, sa_wk + wCC, nullptr, nullptr, kb, M, Cn, Cn);
    gemm64<0, 0><<<gemmGrid, 256, 0, stream>>>(a, sa_wv + wCC, nullptr, nullptr, vb, M, Cn, Cn);
    attn_self<<<4096, 256, 0, stream>>>(qb, kb, vb, ao);
    gemm64<0, 2><<<gemmGrid, 256, 0, stream>>>(ao, sa_wo + wCC, sa_bo + i * Cn, t, t, M, Cn, Cn);
    // --- cross-attention ---
    ln_kernel<<<2048, 256, 0, stream>>>(t, ln2_s + i * Cn, ln2_b + i * Cn, a);
    gemm64<0, 0><<<gemmGrid, 256, 0, stream>>>(a, ca_wq + wCC, nullptr, nullptr, qb, M, Cn, Cn);
    gemm64<0, 0><<<dim3(8, 10), 256, 0, stream>>>(cond, ca_wk + wDC, nullptr, nullptr, kb, Bn * NCn, DCn, Cn);
    gemm64<0, 0><<<dim3(8, 10), 256, 0, stream>>>(cond, ca_wv + wDC, nullptr, nullptr, vb, Bn * NCn, DCn, Cn);
    attn_cross<<<4096, 256, 0, stream>>>(qb, kb, vb, ao);
    gemm64<0, 2><<<gemmGrid, 256, 0, stream>>>(ao, ca_wo + wCC, ca_bo + i * Cn, t, t, M, Cn, Cn);
    // --- GEGLU FF ---
    ln_kernel<<<2048, 256, 0, stream>>>(t, ln3_s + i * Cn, ln3_b + i * Cn, a);
    ff_gate<<<dim3(32, 128), 256, 0, stream>>>(a, ff_w1 + (size_t)i * Cn * 4096, ff_b1 + i * 4096, g, M, Cn);
    gemm64<0, 2><<<gemmGrid, 256, 0, stream>>>(g, ff_w2 + (size_t)i * 2048 * Cn, ff_b2 + i * Cn, t, t, M, 2048, Cn);
  }

  // proj_out -> qb (B,S,C), then transpose + pout_b + x residual -> out (B,C,HW)
  gemm64<0, 0><<<gemmGrid, 256, 0, stream>>>(t, pout_w, nullptr, nullptr, qb, M, Cn, Cn);
  trans_add<<<dim3(32, 16, 8), 256, 0, stream>>>(qb, pout_b, x, (float*)d_out);
}

// Round 3
// 2371.240 us; speedup vs baseline: 1.8979x; 1.8979x over previous
//
#include <hip/hip_runtime.h>
#include <math.h>

static constexpr int Bn  = 8;
static constexpr int Cn  = 512;
static constexpr int HWn = 1024;   // 32*32
static constexpr int Sn  = 1024;   // seq len
static constexpr int NCn = 77;
static constexpr int NCp = 640;    // padded cond rows (8*77=616 -> 640)
static constexpr int DCn = 768;

typedef unsigned short u16;
typedef __attribute__((ext_vector_type(8))) short short8v;   // 8 bf16 (4 VGPRs)
typedef __attribute__((ext_vector_type(4))) float f32x4;
typedef __attribute__((ext_vector_type(8))) unsigned short u16x8;

__device__ __forceinline__ u16 f2b(float f) {
  unsigned u = __float_as_uint(f);
  return (u16)((u + 0x7fffu + ((u >> 16) & 1u)) >> 16);
}
__device__ __forceinline__ float b2f(u16 h) {
  return __uint_as_float(((unsigned)h) << 16);
}

#define GLDS16(gp, lp) __builtin_amdgcn_global_load_lds( \
    (const __attribute__((address_space(1))) void*)(gp),  \
    (__attribute__((address_space(3))) void*)(lp), 16, 0, 0)

// ======================= weight transpose-cast: (K,N) f32 -> (N,K) bf16 ====================
__global__ __launch_bounds__(256) void w_cast_t(const float* __restrict__ in,
    u16* __restrict__ out, int K, int N)
{
  __shared__ float tile[32][33];
  int k0 = blockIdx.x * 32, n0 = blockIdx.y * 32;
  int px = threadIdx.x & 31, py = threadIdx.x >> 5;
  for (int yy = py; yy < 32; yy += 8)
    tile[yy][px] = in[(size_t)(k0 + yy) * N + n0 + px];
  __syncthreads();
  for (int yy = py; yy < 32; yy += 8)
    out[(size_t)(n0 + yy) * K + k0 + px] = f2b(tile[px][yy]);
}

// ======================= cond cast: (616,768) f32 -> (640,768) bf16, pad=0 =================
__global__ __launch_bounds__(256) void cond_cast(const float* __restrict__ in,
    u16* __restrict__ out)
{
  int idx = blockIdx.x * 256 + threadIdx.x;        // 640*768 total
  int m = idx / DCn;
  out[idx] = (m < Bn * NCn) ? f2b(in[idx]) : (u16)0;
}

// ======================= elementwise f32 -> bf16 (vec8) ====================================
__global__ __launch_bounds__(256) void cast_f2b8(const float* __restrict__ in,
    u16* __restrict__ out)
{
  int i = blockIdx.x * 256 + threadIdx.x;          // covers n/8
  const float4* p = (const float4*)(in + (size_t)i * 8);
  float4 a = p[0], b = p[1];
  u16x8 o;
  o[0] = f2b(a.x); o[1] = f2b(a.y); o[2] = f2b(a.z); o[3] = f2b(a.w);
  o[4] = f2b(b.x); o[5] = f2b(b.y); o[6] = f2b(b.z); o[7] = f2b(b.w);
  *(u16x8*)(out + (size_t)i * 8) = o;
}

// ======================= GroupNorm: (B,C,H,W) -> (B,C,HW) normalized fp32 ==================
__global__ __launch_bounds__(256) void gn_kernel(const float* __restrict__ x,
    const float* __restrict__ gs, const float* __restrict__ gb, float* __restrict__ out)
{
  int b = blockIdx.x >> 5, g = blockIdx.x & 31;
  const float* xp = x + ((size_t)b * Cn + g * 16) * HWn;
  float s = 0.f, ss = 0.f;
  for (int e = threadIdx.x; e < 16 * HWn; e += 256) {
    float v = xp[e];
    s += v; ss += v * v;
  }
  __shared__ float red[10];
  #pragma unroll
  for (int o = 32; o; o >>= 1) { s += __shfl_xor(s, o, 64); ss += __shfl_xor(ss, o, 64); }
  if ((threadIdx.x & 63) == 0) { red[threadIdx.x >> 6] = s; red[(threadIdx.x >> 6) + 4] = ss; }
  __syncthreads();
  if (threadIdx.x == 0) {
    float st  = red[0] + red[1] + red[2] + red[3];
    float sst = red[4] + red[5] + red[6] + red[7];
    float mu  = st * (1.f / 16384.f);
    red[8] = mu;
    red[9] = rsqrtf(sst * (1.f / 16384.f) - mu * mu + 1e-6f);
  }
  __syncthreads();
  float mu = red[8], inv = red[9];
  float* op = out + ((size_t)b * Cn + g * 16) * HWn;
  for (int e = threadIdx.x; e < 16 * HWn; e += 256) {
    int cl = e >> 10;
    op[e] = (xp[e] - mu) * inv * gs[g * 16 + cl] + gb[g * 16 + cl];
  }
}

// ======================= (B,C,HW) f32 -> (B*HW, C) bf16 transpose ==========================
__global__ __launch_bounds__(256) void gn_t_cast(const float* __restrict__ in,
    u16* __restrict__ out)
{
  __shared__ float tile[32][33];
  int p0 = blockIdx.x * 32, c0 = blockIdx.y * 32, b = blockIdx.z;
  int px = threadIdx.x & 31, py = threadIdx.x >> 5;
  for (int yy = py; yy < 32; yy += 8)
    tile[yy][px] = in[((size_t)b * Cn + c0 + yy) * HWn + p0 + px];
  __syncthreads();
  for (int yy = py; yy < 32; yy += 8)
    out[((size_t)b * HWn + p0 + yy) * Cn + c0 + px] = f2b(tile[px][yy]);
}

// ======================= LayerNorm (512) f32 in -> bf16 out ================================
__global__ __launch_bounds__(256) void ln_kernel(const float* __restrict__ in,
    const float* __restrict__ s, const float* __restrict__ b, u16* __restrict__ out)
{
  int row  = blockIdx.x * 4 + (threadIdx.x >> 6);
  int lane = threadIdx.x & 63;
  const float* ip = in + (size_t)row * Cn + lane * 8;
  float4 v0 = *(const float4*)ip;
  float4 v1 = *(const float4*)(ip + 4);
  float sum = v0.x + v0.y + v0.z + v0.w + v1.x + v1.y + v1.z + v1.w;
  float ss  = v0.x*v0.x + v0.y*v0.y + v0.z*v0.z + v0.w*v0.w
            + v1.x*v1.x + v1.y*v1.y + v1.z*v1.z + v1.w*v1.w;
  #pragma unroll
  for (int o = 32; o; o >>= 1) { sum += __shfl_xor(sum, o, 64); ss += __shfl_xor(ss, o, 64); }
  float mu  = sum * (1.f / Cn);
  float inv = rsqrtf(ss * (1.f / Cn) - mu * mu + 1e-5f);
  const float4 s0 = *(const float4*)(s + lane * 8);
  const float4 s1 = *(const float4*)(s + lane * 8 + 4);
  const float4 b0 = *(const float4*)(b + lane * 8);
  const float4 b1 = *(const float4*)(b + lane * 8 + 4);
  u16x8 o;
  o[0] = f2b((v0.x - mu) * inv * s0.x + b0.x);
  o[1] = f2b((v0.y - mu) * inv * s0.y + b0.y);
  o[2] = f2b((v0.z - mu) * inv * s0.z + b0.z);
  o[3] = f2b((v0.w - mu) * inv * s0.w + b0.w);
  o[4] = f2b((v1.x - mu) * inv * s1.x + b1.x);
  o[5] = f2b((v1.y - mu) * inv * s1.y + b1.y);
  o[6] = f2b((v1.z - mu) * inv * s1.z + b1.z);
  o[7] = f2b((v1.w - mu) * inv * s1.w + b1.w);
  *(u16x8*)(out + (size_t)row * Cn + lane * 8) = o;
}

// ======================= MFMA GEMM: out_f32 = A_bf16 @ Wt_bf16^T (+bias)(+res) =============
// A (M,K) bf16 row-major; Wt (N,K) bf16 row-major. 128x128 tile, BK=32, 4 waves.
// EPI: 0 none, 1 +bias, 2 +bias+res.
template<int EPI>
__global__ __launch_bounds__(256) void gemm_mfma(const u16* __restrict__ A,
    const u16* __restrict__ Bt, const float* __restrict__ bias,
    const float* __restrict__ res, float* __restrict__ out, int M, int K, int N)
{
  __shared__ __align__(16) u16 As[128 * 32];
  __shared__ __align__(16) u16 Bs[128 * 32];
  int tid = threadIdx.x, lane = tid & 63, wid = tid >> 6;
  int n0 = blockIdx.x * 128, m0 = blockIdx.y * 128;
  int wr = wid >> 1, wc = wid & 1;
  int r16 = lane & 15, q4 = lane >> 4;
  f32x4 acc[4][4] = {};
  for (int k0 = 0; k0 < K; k0 += 32) {
    #pragma unroll
    for (int i = 0; i < 2; i++) {
      int c = wid * 128 + i * 64 + lane;                 // chunk: row=c>>2, sub=c&3
      size_t ldso = (size_t)(wid * 2 + i) * 1024;
      GLDS16(A  + (size_t)(m0 + (c >> 2)) * K + k0 + (c & 3) * 8, (char*)As + ldso);
      GLDS16(Bt + (size_t)(n0 + (c >> 2)) * K + k0 + (c & 3) * 8, (char*)Bs + ldso);
    }
    __syncthreads();
    short8v a[4], b[4];
    #pragma unroll
    for (int m = 0; m < 4; m++)
      a[m] = *(const short8v*)((const char*)As + (wr * 64 + m * 16 + r16) * 64 + q4 * 16);
    #pragma unroll
    for (int n = 0; n < 4; n++)
      b[n] = *(const short8v*)((const char*)Bs + (wc * 64 + n * 16 + r16) * 64 + q4 * 16);
    #pragma unroll
    for (int m = 0; m < 4; m++)
      #pragma unroll
      for (int n = 0; n < 4; n++)
        acc[m][n] = __builtin_amdgcn_mfma_f32_16x16x32_bf16(a[m], b[n], acc[m][n], 0, 0, 0);
    __syncthreads();
  }
  #pragma unroll
  for (int m = 0; m < 4; m++) {
    int gm0 = m0 + wr * 64 + m * 16 + q4 * 4;
    #pragma unroll
    for (int n = 0; n < 4; n++) {
      int gc = n0 + wc * 64 + n * 16 + r16;
      float bv = (EPI >= 1) ? bias[gc] : 0.f;
      #pragma unroll
      for (int r = 0; r < 4; r++) {
        float v = acc[m][n][r] + bv;
        size_t oi = (size_t)(gm0 + r) * N + gc;
        if (EPI == 2) v += res[oi];
        out[oi] = v;
      }
    }
  }
}

// ======================= Fused GEGLU MFMA GEMM =============================================
// A (M,512) bf16, W1t (4096,512) bf16 (rows 0..2047 = u, 2048..4095 = gate).
// out (M,2048) bf16 = (u+bu) * gelu(g+bg).
__global__ __launch_bounds__(256) void ff_gate_mfma(const u16* __restrict__ A,
    const u16* __restrict__ W1t, const float* __restrict__ bias,
    u16* __restrict__ out, int M, int K)
{
  __shared__ __align__(16) u16 As[128 * 32];
  __shared__ __align__(16) u16 Bu[128 * 32];
  __shared__ __align__(16) u16 Bg[128 * 32];
  int tid = threadIdx.x, lane = tid & 63, wid = tid >> 6;
  int n0 = blockIdx.x * 128, m0 = blockIdx.y * 128;
  int wr = wid >> 1, wc = wid & 1;
  int r16 = lane & 15, q4 = lane >> 4;
  f32x4 au[4][4] = {}, ag[4][4] = {};
  for (int k0 = 0; k0 < K; k0 += 32) {
    #pragma unroll
    for (int i = 0; i < 2; i++) {
      int c = wid * 128 + i * 64 + lane;
      size_t ldso = (size_t)(wid * 2 + i) * 1024;
      int row = c >> 2, sub = (c & 3) * 8;
      GLDS16(A   + (size_t)(m0 + row) * K + k0 + sub,          (char*)As + ldso);
      GLDS16(W1t + (size_t)(n0 + row) * K + k0 + sub,          (char*)Bu + ldso);
      GLDS16(W1t + (size_t)(2048 + n0 + row) * K + k0 + sub,   (char*)Bg + ldso);
    }
    __syncthreads();
    short8v a[4], bu[4], bg[4];
    #pragma unroll
    for (int m = 0; m < 4; m++)
      a[m] = *(const short8v*)((const char*)As + (wr * 64 + m * 16 + r16) * 64 + q4 * 16);
    #pragma unroll
    for (int n = 0; n < 4; n++) {
      bu[n] = *(const short8v*)((const char*)Bu + (wc * 64 + n * 16 + r16) * 64 + q4 * 16);
      bg[n] = *(const short8v*)((const char*)Bg + (wc * 64 + n * 16 + r16) * 64 + q4 * 16);
    }
    #pragma unroll
    for (int m = 0; m < 4; m++)
      #pragma unroll
      for (int n = 0; n < 4; n++) {
        au[m][n] = __builtin_amdgcn_mfma_f32_16x16x32_bf16(a[m], bu[n], au[m][n], 0, 0, 0);
        ag[m][n] = __builtin_amdgcn_mfma_f32_16x16x32_bf16(a[m], bg[n], ag[m][n], 0, 0, 0);
      }
    __syncthreads();
  }
  #pragma unroll
  for (int m = 0; m < 4; m++) {
    int gm0 = m0 + wr * 64 + m * 16 + q4 * 4;
    #pragma unroll
    for (int n = 0; n < 4; n++) {
      int gc = n0 + wc * 64 + n * 16 + r16;
      float bu_ = bias[gc], bg_ = bias[2048 + gc];
      #pragma unroll
      for (int r = 0; r < 4; r++) {
        float u = au[m][n][r] + bu_;
        float g = ag[m][n][r] + bg_;
        float ge = 0.5f * g * (1.f + erff(g * 0.70710678118f));
        out[(size_t)(gm0 + r) * 2048 + gc] = f2b(u * ge);
      }
    }
  }
}

// ======================= Self-attention (bf16 scores in LDS, bf16 out) =====================
__global__ __launch_bounds__(256) void attn_self(const float* __restrict__ q,
    const float* __restrict__ k, const float* __restrict__ v, u16* __restrict__ o)
{
  int blk = blockIdx.x;
  int i0 = (blk & 63) << 4;
  int n  = (blk >> 6) & 7;
  int b  = blk >> 9;
  __shared__ float qs[16][64];
  __shared__ u16   sc[16][1024];
  __shared__ float invs[16];
  int tid = threadIdx.x;
  int d = tid & 63, rg = tid >> 6;
  const float* qbase = q + ((size_t)b * Sn + i0) * Cn + n * 64;
  for (int r = rg; r < 16; r += 4) qs[r][d] = qbase[(size_t)r * Cn + d];
  __syncthreads();
  const float* kb = k + (size_t)b * Sn * Cn + n * 64;
  {
    float acc[16][4];
    #pragma unroll
    for (int r = 0; r < 16; r++)
      #pragma unroll
      for (int j = 0; j < 4; j++) acc[r][j] = 0.f;
    int j0 = tid * 4;
    for (int d0 = 0; d0 < 64; d0 += 4) {
      float4 k4[4];
      #pragma unroll
      for (int jj = 0; jj < 4; jj++)
        k4[jj] = *(const float4*)(kb + (size_t)(j0 + jj) * Cn + d0);
      #pragma unroll
      for (int r = 0; r < 16; r++) {
        const float4 q4 = *(const float4*)&qs[r][d0];
        #pragma unroll
        for (int jj = 0; jj < 4; jj++)
          acc[r][jj] += q4.x * k4[jj].x + q4.y * k4[jj].y + q4.z * k4[jj].z + q4.w * k4[jj].w;
      }
    }
    #pragma unroll
    for (int r = 0; r < 16; r++) {
      ushort4 pk;
      pk.x = f2b(acc[r][0]); pk.y = f2b(acc[r][1]);
      pk.z = f2b(acc[r][2]); pk.w = f2b(acc[r][3]);
      *(ushort4*)&sc[r][j0] = pk;
    }
  }
  __syncthreads();
  int lane = tid & 63, wid = tid >> 6;
  for (int r = wid; r < 16; r += 4) {
    float mx = -1e30f;
    for (int j = lane; j < 1024; j += 64) mx = fmaxf(mx, b2f(sc[r][j]));
    #pragma unroll
    for (int off = 32; off; off >>= 1) mx = fmaxf(mx, __shfl_xor(mx, off, 64));
    float sum = 0.f;
    for (int j = lane; j < 1024; j += 64) {
      float p = __expf(b2f(sc[r][j]) - mx);
      sc[r][j] = f2b(p); sum += p;
    }
    #pragma unroll
    for (int off = 32; off; off >>= 1) sum += __shfl_xor(sum, off, 64);
    if (lane == 0) invs[r] = 1.f / sum;
  }
  __syncthreads();
  const float* vbp = v + (size_t)b * Sn * Cn + n * 64;
  float accv[4] = {0.f, 0.f, 0.f, 0.f};
  for (int j0 = 0; j0 < 1024; j0 += 4) {
    float vv[4];
    #pragma unroll
    for (int jj = 0; jj < 4; jj++) vv[jj] = vbp[(size_t)(j0 + jj) * Cn + d];
    #pragma unroll
    for (int ri = 0; ri < 4; ri++) {
      ushort4 p4 = *(const ushort4*)&sc[rg * 4 + ri][j0];
      accv[ri] += b2f(p4.x) * vv[0] + b2f(p4.y) * vv[1] + b2f(p4.z) * vv[2] + b2f(p4.w) * vv[3];
    }
  }
  u16* ob = o + ((size_t)b * Sn + i0) * Cn + n * 64;
  #pragma unroll
  for (int ri = 0; ri < 4; ri++)
    ob[(size_t)(rg * 4 + ri) * Cn + d] = f2b(accv[ri] * invs[rg * 4 + ri]);
}

// ======================= Cross-attention (Sk=77), bf16 out =================================
__global__ __launch_bounds__(256) void attn_cross(const float* __restrict__ q,
    const float* __restrict__ k, const float* __restrict__ v, u16* __restrict__ o)
{
  int blk = blockIdx.x;
  int i0 = (blk & 63) << 4;
  int n  = (blk >> 6) & 7;
  int b  = blk >> 9;
  __shared__ float qs[16][64];
  __shared__ float sc[16][80];
  __shared__ float invs[16];
  int tid = threadIdx.x;
  int d = tid & 63, rg = tid >> 6;
  const float* qbase = q + ((size_t)b * Sn + i0) * Cn + n * 64;
  for (int r = rg; r < 16; r += 4) qs[r][d] = qbase[(size_t)r * Cn + d];
  __syncthreads();
  int r = tid >> 4, t16 = tid & 15;
  const float* kb = k + (size_t)b * NCn * Cn + n * 64;
  for (int j = t16; j < NCn; j += 16) {
    const float* kr = kb + (size_t)j * Cn;
    float acc = 0.f;
    #pragma unroll
    for (int d0 = 0; d0 < 64; d0 += 4) {
      const float4 k4 = *(const float4*)(kr + d0);
      const float4 q4 = *(const float4*)&qs[r][d0];
      acc += q4.x * k4.x + q4.y * k4.y + q4.z * k4.z + q4.w * k4.w;
    }
    sc[r][j] = acc;
  }
  __syncthreads();
  float mx = -1e30f;
  for (int j = t16; j < NCn; j += 16) mx = fmaxf(mx, sc[r][j]);
  #pragma unroll
  for (int off = 8; off; off >>= 1) mx = fmaxf(mx, __shfl_xor(mx, off, 64));
  float sum = 0.f;
  for (int j = t16; j < NCn; j += 16) {
    float p = __expf(sc[r][j] - mx);
    sc[r][j] = p; sum += p;
  }
  #pragma unroll
  for (int off = 8; off; off >>= 1) sum += __shfl_xor(sum, off, 64);
  if (t16 == 0) invs[r] = 1.f / sum;
  __syncthreads();
  const float* vbp = v + (size_t)b * NCn * Cn + n * 64;
  float accv[4] = {0.f, 0.f, 0.f, 0.f};
  for (int j = 0; j < NCn; j++) {
    float vv = vbp[(size_t)j * Cn + d];
    #pragma unroll
    for (int ri = 0; ri < 4; ri++) accv[ri] += sc[rg * 4 + ri][j] * vv;
  }
  u16* ob = o + ((size_t)b * Sn + i0) * Cn + n * 64;
  #pragma unroll
  for (int ri = 0; ri < 4; ri++)
    ob[(size_t)(rg * 4 + ri) * Cn + d] = f2b(accv[ri] * invs[rg * 4 + ri]);
}

// ======================= Transpose (B,HW,C)->(B,C,HW) + pout_b + x_in ======================
__global__ __launch_bounds__(256) void trans_add(const float* __restrict__ tin,
    const float* __restrict__ pb, const float* __restrict__ xin, float* __restrict__ out)
{
  __shared__ float tile[32][33];
  int p0 = blockIdx.x * 32, d0 = blockIdx.y * 32, b = blockIdx.z;
  int px = threadIdx.x & 31, py = threadIdx.x >> 5;
  for (int yy = py; yy < 32; yy += 8)
    tile[yy][px] = tin[((size_t)b * HWn + p0 + yy) * Cn + d0 + px];
  __syncthreads();
  for (int yy = py; yy < 32; yy += 8) {
    int dd = d0 + yy;
    size_t oidx = ((size_t)b * Cn + dd) * HWn + p0 + px;
    out[oidx] = tile[px][yy] + pb[dd] + xin[oidx];
  }
}

// ======================= Launch ============================================================
extern "C" void kernel_launch(void* const* d_in, const int* in_sizes, int n_in,
                              void* d_out, int out_size, void* d_ws, size_t ws_size,
                              hipStream_t stream) {
  const float* x      = (const float*)d_in[0];
  const float* cond   = (const float*)d_in[1];
  const float* gn_s   = (const float*)d_in[2];
  const float* gn_b   = (const float*)d_in[3];
  const float* pin_w  = (const float*)d_in[4];
  const float* pin_b  = (const float*)d_in[5];
  const float* pout_w = (const float*)d_in[6];
  const float* pout_b = (const float*)d_in[7];
  const float* ln1_s  = (const float*)d_in[8];
  const float* ln1_b  = (const float*)d_in[9];
  const float* sa_wq  = (const float*)d_in[10];
  const float* sa_wk  = (const float*)d_in[11];
  const float* sa_wv  = (const float*)d_in[12];
  const float* sa_wo  = (const float*)d_in[13];
  const float* sa_bo  = (const float*)d_in[14];
  const float* ln2_s  = (const float*)d_in[15];
  const float* ln2_b  = (const float*)d_in[16];
  const float* ca_wq  = (const float*)d_in[17];
  const float* ca_wk  = (const float*)d_in[18];
  const float* ca_wv  = (const float*)d_in[19];
  const float* ca_wo  = (const float*)d_in[20];
  const float* ca_bo  = (const float*)d_in[21];
  const float* ln3_s  = (const float*)d_in[22];
  const float* ln3_b  = (const float*)d_in[23];
  const float* ff_w1  = (const float*)d_in[24];
  const float* ff_b1  = (const float*)d_in[25];
  const float* ff_w2  = (const float*)d_in[26];
  const float* ff_b2  = (const float*)d_in[27];

  const int M = Bn * Sn;  // 8192
  const size_t MB = 1ull << 20;
  char* ws = (char*)d_ws;
  // layout: total ~128.2 MB
  float* t     = (float*)(ws);            // 16 MB  fp32 residual stream
  u16*   abf   = (u16*)  (ws + 16 * MB);  //  8 MB  LN out / attn out (bf16)
  float* qb    = (float*)(ws + 24 * MB);  // 16 MB
  float* kb    = (float*)(ws + 40 * MB);  // 16 MB
  float* vb    = (float*)(ws + 56 * MB);  // 16 MB
  u16*   hb    = (u16*)  (ws + 72 * MB);  // 32 MB  GEGLU out (aliases gnout+xb)
  float* gnout = (float*)(ws + 72 * MB);  // 16 MB  (alias, start only)
  u16*   xb    = (u16*)  (ws + 88 * MB);  //  8 MB  (alias; also tb at end)
  u16*   condb = (u16*)  (ws + 104 * MB); //  0.95 MB
  u16*   wts   = (u16*)  (ws + 105 * MB); // ~23.1 MB

  // weight bf16-transpose pointers
  u16* wp = wts;
  u16* pinT  = wp; wp += 512 * 512;
  u16* poutT = wp; wp += 512 * 512;
  u16 *sa_wqT[2], *sa_wkT[2], *sa_wvT[2], *sa_woT[2];
  u16 *ca_wqT[2], *ca_wkT[2], *ca_wvT[2], *ca_woT[2], *ff_w1T[2], *ff_w2T[2];
  for (int i = 0; i < 2; i++) {
    sa_wqT[i] = wp; wp += 512 * 512;
    sa_wkT[i] = wp; wp += 512 * 512;
    sa_wvT[i] = wp; wp += 512 * 512;
    sa_woT[i] = wp; wp += 512 * 512;
    ca_wqT[i] = wp; wp += 512 * 512;
    ca_wkT[i] = wp; wp += 768 * 512;
    ca_wvT[i] = wp; wp += 768 * 512;
    ca_woT[i] = wp; wp += 512 * 512;
    ff_w1T[i] = wp; wp += 512 * 4096;
    ff_w2T[i] = wp; wp += 2048 * 512;
  }

  // ---- weight casts (transpose to (N,K) bf16) ----
  dim3 tcc(16, 16);
  w_cast_t<<<tcc, 256, 0, stream>>>(pin_w, pinT, 512, 512);
  w_cast_t<<<tcc, 256, 0, stream>>>(pout_w, poutT, 512, 512);
  for (int i = 0; i < 2; i++) {
    const size_t wCC = (size_t)i * 512 * 512, wDC = (size_t)i * 768 * 512;
    w_cast_t<<<tcc, 256, 0, stream>>>(sa_wq + wCC, sa_wqT[i], 512, 512);
    w_cast_t<<<tcc, 256, 0, stream>>>(sa_wk + wCC, sa_wkT[i], 512, 512);
    w_cast_t<<<tcc, 256, 0, stream>>>(sa_wv + wCC, sa_wvT[i], 512, 512);
    w_cast_t<<<tcc, 256, 0, stream>>>(sa_wo + wCC, sa_woT[i], 512, 512);
    w_cast_t<<<tcc, 256, 0, stream>>>(ca_wq + wCC, ca_wqT[i], 512, 512);
    w_cast_t<<<dim3(24, 16), 256, 0, stream>>>(ca_wk + wDC, ca_wkT[i], 768, 512);
    w_cast_t<<<dim3(24, 16), 256, 0, stream>>>(ca_wv + wDC, ca_wvT[i], 768, 512);
    w_cast_t<<<tcc, 256, 0, stream>>>(ca_wo + wCC, ca_woT[i], 512, 512);
    w_cast_t<<<dim3(16, 128), 256, 0, stream>>>(ff_w1 + (size_t)i * 512 * 4096, ff_w1T[i], 512, 4096);
    w_cast_t<<<dim3(64, 16), 256, 0, stream>>>(ff_w2 + (size_t)i * 2048 * 512, ff_w2T[i], 2048, 512);
  }
  cond_cast<<<(NCp * DCn) / 256, 256, 0, stream>>>(cond, condb);

  // ---- GN -> transpose/cast -> proj_in ----
  gn_kernel<<<256, 256, 0, stream>>>(x, gn_s, gn_b, gnout);
  gn_t_cast<<<dim3(32, 16, 8), 256, 0, stream>>>(gnout, xb);
  gemm_mfma<1><<<dim3(4, 64), 256, 0, stream>>>(xb, pinT, pin_b, nullptr, t, M, 512, 512);

  for (int i = 0; i < 2; i++) {
    // --- self-attention ---
    ln_kernel<<<2048, 256, 0, stream>>>(t, ln1_s + i * Cn, ln1_b + i * Cn, abf);
    gemm_mfma<0><<<dim3(4, 64), 256, 0, stream>>>(abf, sa_wqT[i], nullptr, nullptr, qb, M, 512, 512);
    gemm_mfma<0><<<dim3(4, 64), 256, 0, stream>>>(abf, sa_wkT[i], nullptr, nullptr, kb, M, 512, 512);
    gemm_mfma<0><<<dim3(4, 64), 256, 0, stream>>>(abf, sa_wvT[i], nullptr, nullptr, vb, M, 512, 512);
    attn_self<<<4096, 256, 0, stream>>>(qb, kb, vb, abf);
    gemm_mfma<2><<<dim3(4, 64), 256, 0, stream>>>(abf, sa_woT[i], sa_bo + i * Cn, t, t, M, 512, 512);
    // --- cross-attention ---
    ln_kernel<<<2048, 256, 0, stream>>>(t, ln2_s + i * Cn, ln2_b + i * Cn, abf);
    gemm_mfma<0><<<dim3(4, 64), 256, 0, stream>>>(abf, ca_wqT[i], nullptr, nullptr, qb, M, 512, 512);
    gemm_mfma<0><<<dim3(4, 5), 256, 0, stream>>>(condb, ca_wkT[i], nullptr, nullptr, kb, NCp, 768, 512);
    gemm_mfma<0><<<dim3(4, 5), 256, 0, stream>>>(condb, ca_wvT[i], nullptr, nullptr, vb, NCp, 768, 512);
    attn_cross<<<4096, 256, 0, stream>>>(qb, kb, vb, abf);
    gemm_mfma<2><<<dim3(4, 64), 256, 0, stream>>>(abf, ca_woT[i], ca_bo + i * Cn, t, t, M, 512, 512);
    // --- GEGLU FF ---
    ln_kernel<<<2048, 256, 0, stream>>>(t, ln3_s + i * Cn, ln3_b + i * Cn, abf);
    ff_gate_mfma<<<dim3(16, 64), 256, 0, stream>>>(abf, ff_w1T[i], ff_b1 + i * 4096, hb, M, 512);
    gemm_mfma<2><<<dim3(4, 64), 256, 0, stream>>>(hb, ff_w2T[i], ff_b2 + i * Cn, t, t, M, 2048, 512);
  }

  // ---- proj_out + residual ----
  cast_f2b8<<<2048, 256, 0, stream>>>(t, xb);   // t -> tb (bf16), reuses xb slot
  gemm_mfma<0><<<dim3(4, 64), 256, 0, stream>>>(xb, poutT, nullptr, nullptr, qb, M, 512, 512);
  trans_add<<<dim3(32, 16, 8), 256, 0, stream>>>(qb, pout_b, x, (float*)d_out);
}

// Round 4
// 1345.464 us; speedup vs baseline: 3.3448x; 1.7624x over previous
//
#include <hip/hip_runtime.h>
#include <math.h>

static constexpr int Bn  = 8;
static constexpr int Cn  = 512;
static constexpr int HWn = 1024;   // 32*32
static constexpr int Sn  = 1024;   // seq len
static constexpr int NCn = 77;
static constexpr int NCp = 640;    // padded cond rows (8*77=616 -> 640)
static constexpr int DCn = 768;

typedef unsigned short u16;
typedef __attribute__((ext_vector_type(8))) short short8v;   // 8 bf16 (4 VGPRs)
typedef __attribute__((ext_vector_type(4))) float f32x4;
typedef __attribute__((ext_vector_type(8))) unsigned short u16x8;

__device__ __forceinline__ u16 f2b(float f) {
  unsigned u = __float_as_uint(f);
  return (u16)((u + 0x7fffu + ((u >> 16) & 1u)) >> 16);
}
__device__ __forceinline__ float b2f(u16 h) {
  return __uint_as_float(((unsigned)h) << 16);
}

#define GLDS16(gp, lp) __builtin_amdgcn_global_load_lds( \
    (const __attribute__((address_space(1))) void*)(gp),  \
    (__attribute__((address_space(3))) void*)(lp), 16, 0, 0)

// ======================= weight transpose-cast: (K,N) f32 -> (N,K) bf16 ====================
__global__ __launch_bounds__(256) void w_cast_t(const float* __restrict__ in,
    u16* __restrict__ out, int K, int N)
{
  __shared__ float tile[32][33];
  int k0 = blockIdx.x * 32, n0 = blockIdx.y * 32;
  int px = threadIdx.x & 31, py = threadIdx.x >> 5;
  for (int yy = py; yy < 32; yy += 8)
    tile[yy][px] = in[(size_t)(k0 + yy) * N + n0 + px];
  __syncthreads();
  for (int yy = py; yy < 32; yy += 8)
    out[(size_t)(n0 + yy) * K + k0 + px] = f2b(tile[px][yy]);
}

// ======================= cond cast: (616,768) f32 -> (640,768) bf16, pad=0 =================
__global__ __launch_bounds__(256) void cond_cast(const float* __restrict__ in,
    u16* __restrict__ out)
{
  int idx = blockIdx.x * 256 + threadIdx.x;        // 640*768 total
  int m = idx / DCn;
  out[idx] = (m < Bn * NCn) ? f2b(in[idx]) : (u16)0;
}

// ======================= elementwise f32 -> bf16 (vec8) ====================================
__global__ __launch_bounds__(256) void cast_f2b8(const float* __restrict__ in,
    u16* __restrict__ out)
{
  int i = blockIdx.x * 256 + threadIdx.x;          // covers n/8
  const float4* p = (const float4*)(in + (size_t)i * 8);
  float4 a = p[0], b = p[1];
  u16x8 o;
  o[0] = f2b(a.x); o[1] = f2b(a.y); o[2] = f2b(a.z); o[3] = f2b(a.w);
  o[4] = f2b(b.x); o[5] = f2b(b.y); o[6] = f2b(b.z); o[7] = f2b(b.w);
  *(u16x8*)(out + (size_t)i * 8) = o;
}

// ======================= GroupNorm: (B,C,H,W) -> (B,C,HW) normalized fp32 ==================
__global__ __launch_bounds__(256) void gn_kernel(const float* __restrict__ x,
    const float* __restrict__ gs, const float* __restrict__ gb, float* __restrict__ out)
{
  int b = blockIdx.x >> 5, g = blockIdx.x & 31;
  const float* xp = x + ((size_t)b * Cn + g * 16) * HWn;
  float s = 0.f, ss = 0.f;
  for (int e = threadIdx.x; e < 16 * HWn; e += 256) {
    float v = xp[e];
    s += v; ss += v * v;
  }
  __shared__ float red[10];
  #pragma unroll
  for (int o = 32; o; o >>= 1) { s += __shfl_xor(s, o, 64); ss += __shfl_xor(ss, o, 64); }
  if ((threadIdx.x & 63) == 0) { red[threadIdx.x >> 6] = s; red[(threadIdx.x >> 6) + 4] = ss; }
  __syncthreads();
  if (threadIdx.x == 0) {
    float st  = red[0] + red[1] + red[2] + red[3];
    float sst = red[4] + red[5] + red[6] + red[7];
    float mu  = st * (1.f / 16384.f);
    red[8] = mu;
    red[9] = rsqrtf(sst * (1.f / 16384.f) - mu * mu + 1e-6f);
  }
  __syncthreads();
  float mu = red[8], inv = red[9];
  float* op = out + ((size_t)b * Cn + g * 16) * HWn;
  for (int e = threadIdx.x; e < 16 * HWn; e += 256) {
    int cl = e >> 10;
    op[e] = (xp[e] - mu) * inv * gs[g * 16 + cl] + gb[g * 16 + cl];
  }
}

// ======================= (B,C,HW) f32 -> (B*HW, C) bf16 transpose ==========================
__global__ __launch_bounds__(256) void gn_t_cast(const float* __restrict__ in,
    u16* __restrict__ out)
{
  __shared__ float tile[32][33];
  int p0 = blockIdx.x * 32, c0 = blockIdx.y * 32, b = blockIdx.z;
  int px = threadIdx.x & 31, py = threadIdx.x >> 5;
  for (int yy = py; yy < 32; yy += 8)
    tile[yy][px] = in[((size_t)b * Cn + c0 + yy) * HWn + p0 + px];
  __syncthreads();
  for (int yy = py; yy < 32; yy += 8)
    out[((size_t)b * HWn + p0 + yy) * Cn + c0 + px] = f2b(tile[px][yy]);
}

// ======================= LayerNorm (512) f32 in -> bf16 out ================================
__global__ __launch_bounds__(256) void ln_kernel(const float* __restrict__ in,
    const float* __restrict__ s, const float* __restrict__ b, u16* __restrict__ out)
{
  int row  = blockIdx.x * 4 + (threadIdx.x >> 6);
  int lane = threadIdx.x & 63;
  const float* ip = in + (size_t)row * Cn + lane * 8;
  float4 v0 = *(const float4*)ip;
  float4 v1 = *(const float4*)(ip + 4);
  float sum = v0.x + v0.y + v0.z + v0.w + v1.x + v1.y + v1.z + v1.w;
  float ss  = v0.x*v0.x + v0.y*v0.y + v0.z*v0.z + v0.w*v0.w
            + v1.x*v1.x + v1.y*v1.y + v1.z*v1.z + v1.w*v1.w;
  #pragma unroll
  for (int o = 32; o; o >>= 1) { sum += __shfl_xor(sum, o, 64); ss += __shfl_xor(ss, o, 64); }
  float mu  = sum * (1.f / Cn);
  float inv = rsqrtf(ss * (1.f / Cn) - mu * mu + 1e-5f);
  const float4 s0 = *(const float4*)(s + lane * 8);
  const float4 s1 = *(const float4*)(s + lane * 8 + 4);
  const float4 b0 = *(const float4*)(b + lane * 8);
  const float4 b1 = *(const float4*)(b + lane * 8 + 4);
  u16x8 o;
  o[0] = f2b((v0.x - mu) * inv * s0.x + b0.x);
  o[1] = f2b((v0.y - mu) * inv * s0.y + b0.y);
  o[2] = f2b((v0.z - mu) * inv * s0.z + b0.z);
  o[3] = f2b((v0.w - mu) * inv * s0.w + b0.w);
  o[4] = f2b((v1.x - mu) * inv * s1.x + b1.x);
  o[5] = f2b((v1.y - mu) * inv * s1.y + b1.y);
  o[6] = f2b((v1.z - mu) * inv * s1.z + b1.z);
  o[7] = f2b((v1.w - mu) * inv * s1.w + b1.w);
  *(u16x8*)(out + (size_t)row * Cn + lane * 8) = o;
}

// ======================= MFMA GEMM =========================================================
// A (M,K) bf16 row-major; Bt (N,K) bf16 row-major. 128x128 tile, BK=32, 4 waves.
// EPI: 0 none, 1 +bias, 2 +bias+res.
// OUT: 0 f32 row-major (M,N); 1 bf16 row-major (M,N); 2 bf16 transposed (b, n, s) with
//      m = b*1024+s  (for V^T production).
template<int EPI, int OUT>
__global__ __launch_bounds__(256) void gemm_mfma(const u16* __restrict__ A,
    const u16* __restrict__ Bt, const float* __restrict__ bias,
    const float* __restrict__ res, void* __restrict__ outp, int M, int K, int N)
{
  __shared__ __align__(16) u16 As[128 * 32];
  __shared__ __align__(16) u16 Bs[128 * 32];
  int tid = threadIdx.x, lane = tid & 63, wid = tid >> 6;
  int n0 = blockIdx.x * 128, m0 = blockIdx.y * 128;
  int wr = wid >> 1, wc = wid & 1;
  int r16 = lane & 15, q4 = lane >> 4;
  f32x4 acc[4][4] = {};
  for (int k0 = 0; k0 < K; k0 += 32) {
    #pragma unroll
    for (int i = 0; i < 2; i++) {
      int c = wid * 128 + i * 64 + lane;                 // chunk: row=c>>2, sub=c&3
      size_t ldso = (size_t)(wid * 2 + i) * 1024;
      GLDS16(A  + (size_t)(m0 + (c >> 2)) * K + k0 + (c & 3) * 8, (char*)As + ldso);
      GLDS16(Bt + (size_t)(n0 + (c >> 2)) * K + k0 + (c & 3) * 8, (char*)Bs + ldso);
    }
    __syncthreads();
    short8v a[4], b[4];
    #pragma unroll
    for (int m = 0; m < 4; m++)
      a[m] = *(const short8v*)((const char*)As + (wr * 64 + m * 16 + r16) * 64 + q4 * 16);
    #pragma unroll
    for (int n = 0; n < 4; n++)
      b[n] = *(const short8v*)((const char*)Bs + (wc * 64 + n * 16 + r16) * 64 + q4 * 16);
    #pragma unroll
    for (int m = 0; m < 4; m++)
      #pragma unroll
      for (int n = 0; n < 4; n++)
        acc[m][n] = __builtin_amdgcn_mfma_f32_16x16x32_bf16(a[m], b[n], acc[m][n], 0, 0, 0);
    __syncthreads();
  }
  #pragma unroll
  for (int m = 0; m < 4; m++) {
    int gm0 = m0 + wr * 64 + m * 16 + q4 * 4;
    #pragma unroll
    for (int n = 0; n < 4; n++) {
      int gc = n0 + wc * 64 + n * 16 + r16;
      float bv = (EPI >= 1) ? bias[gc] : 0.f;
      if (OUT == 2) {
        int bb = gm0 >> 10, s0 = gm0 & 1023;
        ushort4 pk;
        pk.x = f2b(acc[m][n][0] + bv);
        pk.y = f2b(acc[m][n][1] + bv);
        pk.z = f2b(acc[m][n][2] + bv);
        pk.w = f2b(acc[m][n][3] + bv);
        *(ushort4*)((u16*)outp + ((size_t)bb * Cn + gc) * (size_t)Sn + s0) = pk;
      } else {
        #pragma unroll
        for (int r = 0; r < 4; r++) {
          float v = acc[m][n][r] + bv;
          size_t oi = (size_t)(gm0 + r) * N + gc;
          if (EPI == 2) v += res[oi];
          if (OUT == 0) ((float*)outp)[oi] = v;
          else          ((u16*)outp)[oi]   = f2b(v);
        }
      }
    }
  }
}

// ======================= Fused GEGLU MFMA GEMM =============================================
// A (M,512) bf16, W1t (4096,512) bf16 (rows 0..2047 = u, 2048..4095 = gate).
// out (M,2048) bf16 = (u+bu) * gelu(g+bg).
__global__ __launch_bounds__(256) void ff_gate_mfma(const u16* __restrict__ A,
    const u16* __restrict__ W1t, const float* __restrict__ bias,
    u16* __restrict__ out, int M, int K)
{
  __shared__ __align__(16) u16 As[128 * 32];
  __shared__ __align__(16) u16 Bu[128 * 32];
  __shared__ __align__(16) u16 Bg[128 * 32];
  int tid = threadIdx.x, lane = tid & 63, wid = tid >> 6;
  int n0 = blockIdx.x * 128, m0 = blockIdx.y * 128;
  int wr = wid >> 1, wc = wid & 1;
  int r16 = lane & 15, q4 = lane >> 4;
  f32x4 au[4][4] = {}, ag[4][4] = {};
  for (int k0 = 0; k0 < K; k0 += 32) {
    #pragma unroll
    for (int i = 0; i < 2; i++) {
      int c = wid * 128 + i * 64 + lane;
      size_t ldso = (size_t)(wid * 2 + i) * 1024;
      int row = c >> 2, sub = (c & 3) * 8;
      GLDS16(A   + (size_t)(m0 + row) * K + k0 + sub,          (char*)As + ldso);
      GLDS16(W1t + (size_t)(n0 + row) * K + k0 + sub,          (char*)Bu + ldso);
      GLDS16(W1t + (size_t)(2048 + n0 + row) * K + k0 + sub,   (char*)Bg + ldso);
    }
    __syncthreads();
    short8v a[4], bu[4], bg[4];
    #pragma unroll
    for (int m = 0; m < 4; m++)
      a[m] = *(const short8v*)((const char*)As + (wr * 64 + m * 16 + r16) * 64 + q4 * 16);
    #pragma unroll
    for (int n = 0; n < 4; n++) {
      bu[n] = *(const short8v*)((const char*)Bu + (wc * 64 + n * 16 + r16) * 64 + q4 * 16);
      bg[n] = *(const short8v*)((const char*)Bg + (wc * 64 + n * 16 + r16) * 64 + q4 * 16);
    }
    #pragma unroll
    for (int m = 0; m < 4; m++)
      #pragma unroll
      for (int n = 0; n < 4; n++) {
        au[m][n] = __builtin_amdgcn_mfma_f32_16x16x32_bf16(a[m], bu[n], au[m][n], 0, 0, 0);
        ag[m][n] = __builtin_amdgcn_mfma_f32_16x16x32_bf16(a[m], bg[n], ag[m][n], 0, 0, 0);
      }
    __syncthreads();
  }
  #pragma unroll
  for (int m = 0; m < 4; m++) {
    int gm0 = m0 + wr * 64 + m * 16 + q4 * 4;
    #pragma unroll
    for (int n = 0; n < 4; n++) {
      int gc = n0 + wc * 64 + n * 16 + r16;
      float bu_ = bias[gc], bg_ = bias[2048 + gc];
      #pragma unroll
      for (int r = 0; r < 4; r++) {
        float u = au[m][n][r] + bu_;
        float g = ag[m][n][r] + bg_;
        float ge = 0.5f * g * (1.f + erff(g * 0.70710678118f));
        out[(size_t)(gm0 + r) * 2048 + gc] = f2b(u * ge);
      }
    }
  }
}

// ======================= Self-attention: MFMA flash (no 1/sqrt(d) scale) ===================
// grid 1024 = B*NH*(S/64). Block: 4 waves; wave w owns q-rows [w*16, w*16+16).
// q,k: (B*S, 512) bf16. vt: (B, 512, S) bf16 (V transposed per channel). o: (B*S,512) bf16.
// LDS tiles 64 rows x 128B, XOR-swizzled via pre-swizzled global source (m173):
//   linear 16B-unit g holds global col-group g^(row&7); reads XOR the same.
__global__ __launch_bounds__(256) void attn_self_mfma(const u16* __restrict__ q,
    const u16* __restrict__ k, const u16* __restrict__ vt, u16* __restrict__ o)
{
  __shared__ __align__(16) u16 Qs[64 * 64];
  __shared__ __align__(16) u16 Ks[2][64 * 64];
  __shared__ __align__(16) u16 Vs[2][64 * 64];
  __shared__ __align__(16) u16 Ps[4 * 16 * 64];
  int tid = threadIdx.x, lane = tid & 63, wid = tid >> 6;
  int r16 = lane & 15, q4 = lane >> 4;
  int qt = blockIdx.x & 15, h = (blockIdx.x >> 4) & 7, b = blockIdx.x >> 7;

  const u16* qg = q  + ((size_t)(b * Sn + qt * 64)) * Cn + h * 64;
  const u16* kg = k  + ((size_t)b * Sn) * Cn + h * 64;
  const u16* vg = vt + ((size_t)(b * Cn + h * 64)) * Sn;

  // stage a 64x64 bf16 tile (row stride rs u16) with inverse-swizzled source
  #define STAGE_T(dst, gbase, rs) do { \
    _Pragma("unroll") \
    for (int ii = 0; ii < 2; ii++) { \
      int rr = ii * 32 + wid * 8 + (lane >> 3); \
      GLDS16((gbase) + (size_t)rr * (rs) + (((lane & 7) ^ (rr & 7)) << 3), \
             (char*)(dst) + ii * 4096 + wid * 1024); \
    } \
  } while (0)

  STAGE_T(Qs, qg, Cn);
  STAGE_T(Ks[0], kg, Cn);
  STAGE_T(Vs[0], vg, Sn);
  __syncthreads();

  // Q fragments (held in registers all kernel)
  short8v aq[2];
  {
    int qrow = wid * 16 + r16, sx = r16 & 7;
    const char* base = (const char*)Qs + qrow * 128;
    aq[0] = *(const short8v*)(base + ((q4 ^ sx) << 4));
    aq[1] = *(const short8v*)(base + (((4 | q4) ^ sx) << 4));
  }

  float m_r[4] = {-1e30f, -1e30f, -1e30f, -1e30f};
  float l_r[4] = {0.f, 0.f, 0.f, 0.f};
  f32x4 acc_o[4] = {};
  int cur = 0;
  char* pwave = (char*)Ps + wid * 2048;

  for (int t = 0; t < 16; t++) {
    if (t < 15) {
      STAGE_T(Ks[cur ^ 1], kg + (size_t)(t + 1) * 64 * Cn, Cn);
      STAGE_T(Vs[cur ^ 1], vg + (t + 1) * 64, Sn);
    }
    // ---- QK^T: 16x64 scores per wave ----
    f32x4 s4[4];
    #pragma unroll
    for (int n = 0; n < 4; n++) {
      int krow = n * 16 + r16, sx = r16 & 7;
      const char* base = (const char*)Ks[cur] + krow * 128;
      short8v b0 = *(const short8v*)(base + ((q4 ^ sx) << 4));
      short8v b1 = *(const short8v*)(base + (((4 | q4) ^ sx) << 4));
      f32x4 z = {0.f, 0.f, 0.f, 0.f};
      z = __builtin_amdgcn_mfma_f32_16x16x32_bf16(aq[0], b0, z, 0, 0, 0);
      s4[n] = __builtin_amdgcn_mfma_f32_16x16x32_bf16(aq[1], b1, z, 0, 0, 0);
    }
    // ---- online softmax (rows live in 16-lane groups; reduce over lane&15) ----
    #pragma unroll
    for (int r = 0; r < 4; r++) {
      float tm = fmaxf(fmaxf(s4[0][r], s4[1][r]), fmaxf(s4[2][r], s4[3][r]));
      #pragma unroll
      for (int off = 8; off; off >>= 1) tm = fmaxf(tm, __shfl_xor(tm, off, 64));
      float mn = fmaxf(m_r[r], tm);
      float al = __expf(m_r[r] - mn);
      m_r[r] = mn;
      int prow = q4 * 4 + r;
      char* pbase = pwave + prow * 128;
      int sx = (prow & 7) << 4;
      float rs = 0.f;
      #pragma unroll
      for (int n = 0; n < 4; n++) {
        float p = __expf(s4[n][r] - mn);
        rs += p;
        int cb = ((((n << 4) | r16) << 1) ^ sx);
        *(u16*)(pbase + cb) = f2b(p);
      }
      #pragma unroll
      for (int off = 8; off; off >>= 1) rs += __shfl_xor(rs, off, 64);
      l_r[r] = l_r[r] * al + rs;
      #pragma unroll
      for (int n = 0; n < 4; n++) acc_o[n][r] *= al;
    }
    __syncthreads();   // P visible wave-wide (and drains next-tile staging early)
    // ---- PV: O += P(16x64) * V(64x64) ----
    short8v pa0, pa1;
    {
      int sx = r16 & 7;
      const char* base = pwave + r16 * 128;
      pa0 = *(const short8v*)(base + ((q4 ^ sx) << 4));
      pa1 = *(const short8v*)(base + (((4 | q4) ^ sx) << 4));
    }
    #pragma unroll
    for (int n = 0; n < 4; n++) {
      int vrow = n * 16 + r16, sx = r16 & 7;
      const char* base = (const char*)Vs[cur] + vrow * 128;
      short8v v0 = *(const short8v*)(base + ((q4 ^ sx) << 4));
      short8v v1 = *(const short8v*)(base + (((4 | q4) ^ sx) << 4));
      acc_o[n] = __builtin_amdgcn_mfma_f32_16x16x32_bf16(pa0, v0, acc_o[n], 0, 0, 0);
      acc_o[n] = __builtin_amdgcn_mfma_f32_16x16x32_bf16(pa1, v1, acc_o[n], 0, 0, 0);
    }
    __syncthreads();   // all waves done with Ks/Vs[cur]; next tile resident
    cur ^= 1;
  }

  // ---- epilogue: O / l, write bf16 ----
  u16* ob = o + ((size_t)(b * Sn + qt * 64 + wid * 16 + q4 * 4)) * Cn + h * 64;
  #pragma unroll
  for (int r = 0; r < 4; r++) {
    float inv = 1.f / l_r[r];
    #pragma unroll
    for (int n = 0; n < 4; n++)
      ob[(size_t)r * Cn + n * 16 + r16] = f2b(acc_o[n][r] * inv);
  }
  #undef STAGE_T
}

// ======================= Cross-attention (Sk=77), fp32 in, bf16 out ========================
__global__ __launch_bounds__(256) void attn_cross(const float* __restrict__ q,
    const float* __restrict__ k, const float* __restrict__ v, u16* __restrict__ o)
{
  int blk = blockIdx.x;
  int i0 = (blk & 63) << 4;
  int n  = (blk >> 6) & 7;
  int b  = blk >> 9;
  __shared__ float qs[16][64];
  __shared__ float sc[16][80];
  __shared__ float invs[16];
  int tid = threadIdx.x;
  int d = tid & 63, rg = tid >> 6;
  const float* qbase = q + ((size_t)b * Sn + i0) * Cn + n * 64;
  for (int r = rg; r < 16; r += 4) qs[r][d] = qbase[(size_t)r * Cn + d];
  __syncthreads();
  int r = tid >> 4, t16 = tid & 15;
  const float* kb = k + (size_t)b * NCn * Cn + n * 64;
  for (int j = t16; j < NCn; j += 16) {
    const float* kr = kb + (size_t)j * Cn;
    float acc = 0.f;
    #pragma unroll
    for (int d0 = 0; d0 < 64; d0 += 4) {
      const float4 k4 = *(const float4*)(kr + d0);
      const float4 q4 = *(const float4*)&qs[r][d0];
      acc += q4.x * k4.x + q4.y * k4.y + q4.z * k4.z + q4.w * k4.w;
    }
    sc[r][j] = acc;
  }
  __syncthreads();
  float mx = -1e30f;
  for (int j = t16; j < NCn; j += 16) mx = fmaxf(mx, sc[r][j]);
  #pragma unroll
  for (int off = 8; off; off >>= 1) mx = fmaxf(mx, __shfl_xor(mx, off, 64));
  float sum = 0.f;
  for (int j = t16; j < NCn; j += 16) {
    float p = __expf(sc[r][j] - mx);
    sc[r][j] = p; sum += p;
  }
  #pragma unroll
  for (int off = 8; off; off >>= 1) sum += __shfl_xor(sum, off, 64);
  if (t16 == 0) invs[r] = 1.f / sum;
  __syncthreads();
  const float* vbp = v + (size_t)b * NCn * Cn + n * 64;
  float accv[4] = {0.f, 0.f, 0.f, 0.f};
  for (int j = 0; j < NCn; j++) {
    float vv = vbp[(size_t)j * Cn + d];
    #pragma unroll
    for (int ri = 0; ri < 4; ri++) accv[ri] += sc[rg * 4 + ri][j] * vv;
  }
  u16* ob = o + ((size_t)b * Sn + i0) * Cn + n * 64;
  #pragma unroll
  for (int ri = 0; ri < 4; ri++)
    ob[(size_t)(rg * 4 + ri) * Cn + d] = f2b(accv[ri] * invs[rg * 4 + ri]);
}

// ======================= Transpose (B,HW,C)->(B,C,HW) + pout_b + x_in ======================
__global__ __launch_bounds__(256) void trans_add(const float* __restrict__ tin,
    const float* __restrict__ pb, const float* __restrict__ xin, float* __restrict__ out)
{
  __shared__ float tile[32][33];
  int p0 = blockIdx.x * 32, d0 = blockIdx.y * 32, b = blockIdx.z;
  int px = threadIdx.x & 31, py = threadIdx.x >> 5;
  for (int yy = py; yy < 32; yy += 8)
    tile[yy][px] = tin[((size_t)b * HWn + p0 + yy) * Cn + d0 + px];
  __syncthreads();
  for (int yy = py; yy < 32; yy += 8) {
    int dd = d0 + yy;
    size_t oidx = ((size_t)b * Cn + dd) * HWn + p0 + px;
    out[oidx] = tile[px][yy] + pb[dd] + xin[oidx];
  }
}

// ======================= Launch ============================================================
extern "C" void kernel_launch(void* const* d_in, const int* in_sizes, int n_in,
                              void* d_out, int out_size, void* d_ws, size_t ws_size,
                              hipStream_t stream) {
  const float* x      = (const float*)d_in[0];
  const float* cond   = (const float*)d_in[1];
  const float* gn_s   = (const float*)d_in[2];
  const float* gn_b   = (const float*)d_in[3];
  const float* pin_w  = (const float*)d_in[4];
  const float* pin_b  = (const float*)d_in[5];
  const float* pout_w = (const float*)d_in[6];
  const float* pout_b = (const float*)d_in[7];
  const float* ln1_s  = (const float*)d_in[8];
  const float* ln1_b  = (const float*)d_in[9];
  const float* sa_wq  = (const float*)d_in[10];
  const float* sa_wk  = (const float*)d_in[11];
  const float* sa_wv  = (const float*)d_in[12];
  const float* sa_wo  = (const float*)d_in[13];
  const float* sa_bo  = (const float*)d_in[14];
  const float* ln2_s  = (const float*)d_in[15];
  const float* ln2_b  = (const float*)d_in[16];
  const float* ca_wq  = (const float*)d_in[17];
  const float* ca_wk  = (const float*)d_in[18];
  const float* ca_wv  = (const float*)d_in[19];
  const float* ca_wo  = (const float*)d_in[20];
  const float* ca_bo  = (const float*)d_in[21];
  const float* ln3_s  = (const float*)d_in[22];
  const float* ln3_b  = (const float*)d_in[23];
  const float* ff_w1  = (const float*)d_in[24];
  const float* ff_b1  = (const float*)d_in[25];
  const float* ff_w2  = (const float*)d_in[26];
  const float* ff_b2  = (const float*)d_in[27];

  const int M = Bn * Sn;  // 8192
  const size_t MB = 1ull << 20;
  char* ws = (char*)d_ws;
  float* t     = (float*)(ws);            // 16 MB  fp32 residual stream
  u16*   abf   = (u16*)  (ws + 16 * MB);  //  8 MB  LN out / attn out (bf16)
  float* qb    = (float*)(ws + 24 * MB);  // 16 MB  (fp32 cross-attn q; bf16 self q aliases)
  float* kb    = (float*)(ws + 40 * MB);  // 16 MB
  float* vb    = (float*)(ws + 56 * MB);  // 16 MB
  u16*   hb    = (u16*)  (ws + 72 * MB);  // 32 MB  GEGLU out (aliases gnout+xb)
  float* gnout = (float*)(ws + 72 * MB);  // 16 MB  (alias, start only)
  u16*   xb    = (u16*)  (ws + 88 * MB);  //  8 MB  (alias; also tb at end)
  u16*   condb = (u16*)  (ws + 104 * MB); //  0.95 MB
  u16*   wts   = (u16*)  (ws + 105 * MB); // ~23.1 MB

  u16* q16  = (u16*)qb;   // self-attn bf16 Q  (8 MB of the 16 MB slot)
  u16* k16  = (u16*)kb;
  u16* vt16 = (u16*)vb;   // self-attn bf16 V^T (B, C, S)

  // weight bf16-transpose pointers
  u16* wp = wts;
  u16* pinT  = wp; wp += 512 * 512;
  u16* poutT = wp; wp += 512 * 512;
  u16 *sa_wqT[2], *sa_wkT[2], *sa_wvT[2], *sa_woT[2];
  u16 *ca_wqT[2], *ca_wkT[2], *ca_wvT[2], *ca_woT[2], *ff_w1T[2], *ff_w2T[2];
  for (int i = 0; i < 2; i++) {
    sa_wqT[i] = wp; wp += 512 * 512;
    sa_wkT[i] = wp; wp += 512 * 512;
    sa_wvT[i] = wp; wp += 512 * 512;
    sa_woT[i] = wp; wp += 512 * 512;
    ca_wqT[i] = wp; wp += 512 * 512;
    ca_wkT[i] = wp; wp += 768 * 512;
    ca_wvT[i] = wp; wp += 768 * 512;
    ca_woT[i] = wp; wp += 512 * 512;
    ff_w1T[i] = wp; wp += 512 * 4096;
    ff_w2T[i] = wp; wp += 2048 * 512;
  }

  // ---- weight casts (transpose to (N,K) bf16) ----
  dim3 tcc(16, 16);
  w_cast_t<<<tcc, 256, 0, stream>>>(pin_w, pinT, 512, 512);
  w_cast_t<<<tcc, 256, 0, stream>>>(pout_w, poutT, 512, 512);
  for (int i = 0; i < 2; i++) {
    const size_t wCC = (size_t)i * 512 * 512, wDC = (size_t)i * 768 * 512;
    w_cast_t<<<tcc, 256, 0, stream>>>(sa_wq + wCC, sa_wqT[i], 512, 512);
    w_cast_t<<<tcc, 256, 0, stream>>>(sa_wk + wCC, sa_wkT[i], 512, 512);
    w_cast_t<<<tcc, 256, 0, stream>>>(sa_wv + wCC, sa_wvT[i], 512, 512);
    w_cast_t<<<tcc, 256, 0, stream>>>(sa_wo + wCC, sa_woT[i], 512, 512);
    w_cast_t<<<tcc, 256, 0, stream>>>(ca_wq + wCC, ca_wqT[i], 512, 512);
    w_cast_t<<<dim3(24, 16), 256, 0, stream>>>(ca_wk + wDC, ca_wkT[i], 768, 512);
    w_cast_t<<<dim3(24, 16), 256, 0, stream>>>(ca_wv + wDC, ca_wvT[i], 768, 512);
    w_cast_t<<<tcc, 256, 0, stream>>>(ca_wo + wCC, ca_woT[i], 512, 512);
    w_cast_t<<<dim3(16, 128), 256, 0, stream>>>(ff_w1 + (size_t)i * 512 * 4096, ff_w1T[i], 512, 4096);
    w_cast_t<<<dim3(64, 16), 256, 0, stream>>>(ff_w2 + (size_t)i * 2048 * 512, ff_w2T[i], 2048, 512);
  }
  cond_cast<<<(NCp * DCn) / 256, 256, 0, stream>>>(cond, condb);

  // ---- GN -> transpose/cast -> proj_in ----
  gn_kernel<<<256, 256, 0, stream>>>(x, gn_s, gn_b, gnout);
  gn_t_cast<<<dim3(32, 16, 8), 256, 0, stream>>>(gnout, xb);
  gemm_mfma<1, 0><<<dim3(4, 64), 256, 0, stream>>>(xb, pinT, pin_b, nullptr, t, M, 512, 512);

  for (int i = 0; i < 2; i++) {
    // --- self-attention (bf16 MFMA flash) ---
    ln_kernel<<<2048, 256, 0, stream>>>(t, ln1_s + i * Cn, ln1_b + i * Cn, abf);
    gemm_mfma<0, 1><<<dim3(4, 64), 256, 0, stream>>>(abf, sa_wqT[i], nullptr, nullptr, q16, M, 512, 512);
    gemm_mfma<0, 1><<<dim3(4, 64), 256, 0, stream>>>(abf, sa_wkT[i], nullptr, nullptr, k16, M, 512, 512);
    gemm_mfma<0, 2><<<dim3(4, 64), 256, 0, stream>>>(abf, sa_wvT[i], nullptr, nullptr, vt16, M, 512, 512);
    attn_self_mfma<<<1024, 256, 0, stream>>>(q16, k16, vt16, abf);
    gemm_mfma<2, 0><<<dim3(4, 64), 256, 0, stream>>>(abf, sa_woT[i], sa_bo + i * Cn, t, t, M, 512, 512);
    // --- cross-attention (fp32 path, small) ---
    ln_kernel<<<2048, 256, 0, stream>>>(t, ln2_s + i * Cn, ln2_b + i * Cn, abf);
    gemm_mfma<0, 0><<<dim3(4, 64), 256, 0, stream>>>(abf, ca_wqT[i], nullptr, nullptr, qb, M, 512, 512);
    gemm_mfma<0, 0><<<dim3(4, 5), 256, 0, stream>>>(condb, ca_wkT[i], nullptr, nullptr, kb, NCp, 768, 512);
    gemm_mfma<0, 0><<<dim3(4, 5), 256, 0, stream>>>(condb, ca_wvT[i], nullptr, nullptr, vb, NCp, 768, 512);
    attn_cross<<<4096, 256, 0, stream>>>(qb, kb, vb, abf);
    gemm_mfma<2, 0><<<dim3(4, 64), 256, 0, stream>>>(abf, ca_woT[i], ca_bo + i * Cn, t, t, M, 512, 512);
    // --- GEGLU FF ---
    ln_kernel<<<2048, 256, 0, stream>>>(t, ln3_s + i * Cn, ln3_b + i * Cn, abf);
    ff_gate_mfma<<<dim3(16, 64), 256, 0, stream>>>(abf, ff_w1T[i], ff_b1 + i * 4096, hb, M, 512);
    gemm_mfma<2, 0><<<dim3(4, 64), 256, 0, stream>>>(hb, ff_w2T[i], ff_b2 + i * Cn, t, t, M, 2048, 512);
  }

  // ---- proj_out + residual ----
  cast_f2b8<<<2048, 256, 0, stream>>>(t, xb);   // t -> bf16, reuses xb slot
  gemm_mfma<0, 0><<<dim3(4, 64), 256, 0, stream>>>(xb, poutT, nullptr, nullptr, qb, M, 512, 512);
  trans_add<<<dim3(32, 16, 8), 256, 0, stream>>>(qb, pout_b, x, (float*)d_out);
}

// Round 5
// 1122.615 us; speedup vs baseline: 4.0087x; 1.1985x over previous
//
#include <hip/hip_runtime.h>
#include <math.h>

static constexpr int Bn  = 8;
static constexpr int Cn  = 512;
static constexpr int HWn = 1024;   // 32*32
static constexpr int Sn  = 1024;   // seq len
static constexpr int NCn = 77;
static constexpr int NCp = 640;    // padded cond rows (8*77=616 -> 640)
static constexpr int DCn = 768;

typedef unsigned short u16;
typedef __attribute__((ext_vector_type(8))) short short8v;   // 8 bf16 (4 VGPRs)
typedef __attribute__((ext_vector_type(4))) float f32x4;
typedef __attribute__((ext_vector_type(8))) unsigned short u16x8;

__device__ __forceinline__ u16 f2b(float f) {
  unsigned u = __float_as_uint(f);
  return (u16)((u + 0x7fffu + ((u >> 16) & 1u)) >> 16);
}
__device__ __forceinline__ float b2f(u16 h) {
  return __uint_as_float(((unsigned)h) << 16);
}

#define GLDS16(gp, lp) __builtin_amdgcn_global_load_lds( \
    (const __attribute__((address_space(1))) void*)(gp),  \
    (__attribute__((address_space(3))) void*)(lp), 16, 0, 0)

// ======================= weight transpose-cast: (K,N) f32 -> (N,K) bf16 ====================
__global__ __launch_bounds__(256) void w_cast_t(const float* __restrict__ in,
    u16* __restrict__ out, int K, int N)
{
  __shared__ float tile[32][33];
  int k0 = blockIdx.x * 32, n0 = blockIdx.y * 32;
  int px = threadIdx.x & 31, py = threadIdx.x >> 5;
  for (int yy = py; yy < 32; yy += 8)
    tile[yy][px] = in[(size_t)(k0 + yy) * N + n0 + px];
  __syncthreads();
  for (int yy = py; yy < 32; yy += 8)
    out[(size_t)(n0 + yy) * K + k0 + px] = f2b(tile[px][yy]);
}

// ======================= cond cast: (616,768) f32 -> (640,768) bf16, pad=0 =================
__global__ __launch_bounds__(256) void cond_cast(const float* __restrict__ in,
    u16* __restrict__ out)
{
  int idx = blockIdx.x * 256 + threadIdx.x;        // 640*768 total
  int m = idx / DCn;
  out[idx] = (m < Bn * NCn) ? f2b(in[idx]) : (u16)0;
}

// ======================= elementwise f32 -> bf16 (vec8) ====================================
__global__ __launch_bounds__(256) void cast_f2b8(const float* __restrict__ in,
    u16* __restrict__ out)
{
  int i = blockIdx.x * 256 + threadIdx.x;          // covers n/8
  const float4* p = (const float4*)(in + (size_t)i * 8);
  float4 a = p[0], b = p[1];
  u16x8 o;
  o[0] = f2b(a.x); o[1] = f2b(a.y); o[2] = f2b(a.z); o[3] = f2b(a.w);
  o[4] = f2b(b.x); o[5] = f2b(b.y); o[6] = f2b(b.z); o[7] = f2b(b.w);
  *(u16x8*)(out + (size_t)i * 8) = o;
}

// ======================= GroupNorm: (B,C,H,W) -> (B,C,HW) normalized fp32 ==================
__global__ __launch_bounds__(256) void gn_kernel(const float* __restrict__ x,
    const float* __restrict__ gs, const float* __restrict__ gb, float* __restrict__ out)
{
  int b = blockIdx.x >> 5, g = blockIdx.x & 31;
  const float* xp = x + ((size_t)b * Cn + g * 16) * HWn;
  float s = 0.f, ss = 0.f;
  for (int e = threadIdx.x; e < 16 * HWn; e += 256) {
    float v = xp[e];
    s += v; ss += v * v;
  }
  __shared__ float red[10];
  #pragma unroll
  for (int o = 32; o; o >>= 1) { s += __shfl_xor(s, o, 64); ss += __shfl_xor(ss, o, 64); }
  if ((threadIdx.x & 63) == 0) { red[threadIdx.x >> 6] = s; red[(threadIdx.x >> 6) + 4] = ss; }
  __syncthreads();
  if (threadIdx.x == 0) {
    float st  = red[0] + red[1] + red[2] + red[3];
    float sst = red[4] + red[5] + red[6] + red[7];
    float mu  = st * (1.f / 16384.f);
    red[8] = mu;
    red[9] = rsqrtf(sst * (1.f / 16384.f) - mu * mu + 1e-6f);
  }
  __syncthreads();
  float mu = red[8], inv = red[9];
  float* op = out + ((size_t)b * Cn + g * 16) * HWn;
  for (int e = threadIdx.x; e < 16 * HWn; e += 256) {
    int cl = e >> 10;
    op[e] = (xp[e] - mu) * inv * gs[g * 16 + cl] + gb[g * 16 + cl];
  }
}

// ======================= (B,C,HW) f32 -> (B*HW, C) bf16 transpose ==========================
__global__ __launch_bounds__(256) void gn_t_cast(const float* __restrict__ in,
    u16* __restrict__ out)
{
  __shared__ float tile[32][33];
  int p0 = blockIdx.x * 32, c0 = blockIdx.y * 32, b = blockIdx.z;
  int px = threadIdx.x & 31, py = threadIdx.x >> 5;
  for (int yy = py; yy < 32; yy += 8)
    tile[yy][px] = in[((size_t)b * Cn + c0 + yy) * HWn + p0 + px];
  __syncthreads();
  for (int yy = py; yy < 32; yy += 8)
    out[((size_t)b * HWn + p0 + yy) * Cn + c0 + px] = f2b(tile[px][yy]);
}

// ======================= LayerNorm (512) f32 in -> bf16 out ================================
__global__ __launch_bounds__(256) void ln_kernel(const float* __restrict__ in,
    const float* __restrict__ s, const float* __restrict__ b, u16* __restrict__ out)
{
  int row  = blockIdx.x * 4 + (threadIdx.x >> 6);
  int lane = threadIdx.x & 63;
  const float* ip = in + (size_t)row * Cn + lane * 8;
  float4 v0 = *(const float4*)ip;
  float4 v1 = *(const float4*)(ip + 4);
  float sum = v0.x + v0.y + v0.z + v0.w + v1.x + v1.y + v1.z + v1.w;
  float ss  = v0.x*v0.x + v0.y*v0.y + v0.z*v0.z + v0.w*v0.w
            + v1.x*v1.x + v1.y*v1.y + v1.z*v1.z + v1.w*v1.w;
  #pragma unroll
  for (int o = 32; o; o >>= 1) { sum += __shfl_xor(sum, o, 64); ss += __shfl_xor(ss, o, 64); }
  float mu  = sum * (1.f / Cn);
  float inv = rsqrtf(ss * (1.f / Cn) - mu * mu + 1e-5f);
  const float4 s0 = *(const float4*)(s + lane * 8);
  const float4 s1 = *(const float4*)(s + lane * 8 + 4);
  const float4 b0 = *(const float4*)(b + lane * 8);
  const float4 b1 = *(const float4*)(b + lane * 8 + 4);
  u16x8 o;
  o[0] = f2b((v0.x - mu) * inv * s0.x + b0.x);
  o[1] = f2b((v0.y - mu) * inv * s0.y + b0.y);
  o[2] = f2b((v0.z - mu) * inv * s0.z + b0.z);
  o[3] = f2b((v0.w - mu) * inv * s0.w + b0.w);
  o[4] = f2b((v1.x - mu) * inv * s1.x + b1.x);
  o[5] = f2b((v1.y - mu) * inv * s1.y + b1.y);
  o[6] = f2b((v1.z - mu) * inv * s1.z + b1.z);
  o[7] = f2b((v1.w - mu) * inv * s1.w + b1.w);
  *(u16x8*)(out + (size_t)row * Cn + lane * 8) = o;
}

// ======================= MFMA GEMM =========================================================
// A (M,K) bf16 row-major; Bt (N,K) bf16 row-major. 128x128 tile, BK=32, 4 waves.
// EPI: 0 none, 1 +bias, 2 +bias+res.
// OUT: 0 f32 row-major (M,N); 1 bf16 row-major (M,N); 2 bf16 transposed (b, n, s) with
//      m = b*1024+s  (for V^T production).
template<int EPI, int OUT>
__global__ __launch_bounds__(256) void gemm_mfma(const u16* __restrict__ A,
    const u16* __restrict__ Bt, const float* __restrict__ bias,
    const float* __restrict__ res, void* __restrict__ outp, int M, int K, int N)
{
  __shared__ __align__(16) u16 As[128 * 32];
  __shared__ __align__(16) u16 Bs[128 * 32];
  int tid = threadIdx.x, lane = tid & 63, wid = tid >> 6;
  int n0 = blockIdx.x * 128, m0 = blockIdx.y * 128;
  int wr = wid >> 1, wc = wid & 1;
  int r16 = lane & 15, q4 = lane >> 4;
  f32x4 acc[4][4] = {};
  for (int k0 = 0; k0 < K; k0 += 32) {
    #pragma unroll
    for (int i = 0; i < 2; i++) {
      int c = wid * 128 + i * 64 + lane;                 // chunk: row=c>>2, sub=c&3
      size_t ldso = (size_t)(wid * 2 + i) * 1024;
      GLDS16(A  + (size_t)(m0 + (c >> 2)) * K + k0 + (c & 3) * 8, (char*)As + ldso);
      GLDS16(Bt + (size_t)(n0 + (c >> 2)) * K + k0 + (c & 3) * 8, (char*)Bs + ldso);
    }
    __syncthreads();
    short8v a[4], b[4];
    #pragma unroll
    for (int m = 0; m < 4; m++)
      a[m] = *(const short8v*)((const char*)As + (wr * 64 + m * 16 + r16) * 64 + q4 * 16);
    #pragma unroll
    for (int n = 0; n < 4; n++)
      b[n] = *(const short8v*)((const char*)Bs + (wc * 64 + n * 16 + r16) * 64 + q4 * 16);
    #pragma unroll
    for (int m = 0; m < 4; m++)
      #pragma unroll
      for (int n = 0; n < 4; n++)
        acc[m][n] = __builtin_amdgcn_mfma_f32_16x16x32_bf16(a[m], b[n], acc[m][n], 0, 0, 0);
    __syncthreads();
  }
  #pragma unroll
  for (int m = 0; m < 4; m++) {
    int gm0 = m0 + wr * 64 + m * 16 + q4 * 4;
    #pragma unroll
    for (int n = 0; n < 4; n++) {
      int gc = n0 + wc * 64 + n * 16 + r16;
      float bv = (EPI >= 1) ? bias[gc] : 0.f;
      if (OUT == 2) {
        int bb = gm0 >> 10, s0 = gm0 & 1023;
        ushort4 pk;
        pk.x = f2b(acc[m][n][0] + bv);
        pk.y = f2b(acc[m][n][1] + bv);
        pk.z = f2b(acc[m][n][2] + bv);
        pk.w = f2b(acc[m][n][3] + bv);
        *(ushort4*)((u16*)outp + ((size_t)bb * Cn + gc) * (size_t)Sn + s0) = pk;
      } else {
        #pragma unroll
        for (int r = 0; r < 4; r++) {
          float v = acc[m][n][r] + bv;
          size_t oi = (size_t)(gm0 + r) * N + gc;
          if (EPI == 2) v += res[oi];
          if (OUT == 0) ((float*)outp)[oi] = v;
          else          ((u16*)outp)[oi]   = f2b(v);
        }
      }
    }
  }
}

// ======================= Fused GEGLU MFMA GEMM =============================================
// A (M,512) bf16, W1t (4096,512) bf16 (rows 0..2047 = u, 2048..4095 = gate).
// out (M,2048) bf16 = (u+bu) * gelu(g+bg).
__global__ __launch_bounds__(256) void ff_gate_mfma(const u16* __restrict__ A,
    const u16* __restrict__ W1t, const float* __restrict__ bias,
    u16* __restrict__ out, int M, int K)
{
  __shared__ __align__(16) u16 As[128 * 32];
  __shared__ __align__(16) u16 Bu[128 * 32];
  __shared__ __align__(16) u16 Bg[128 * 32];
  int tid = threadIdx.x, lane = tid & 63, wid = tid >> 6;
  int n0 = blockIdx.x * 128, m0 = blockIdx.y * 128;
  int wr = wid >> 1, wc = wid & 1;
  int r16 = lane & 15, q4 = lane >> 4;
  f32x4 au[4][4] = {}, ag[4][4] = {};
  for (int k0 = 0; k0 < K; k0 += 32) {
    #pragma unroll
    for (int i = 0; i < 2; i++) {
      int c = wid * 128 + i * 64 + lane;
      size_t ldso = (size_t)(wid * 2 + i) * 1024;
      int row = c >> 2, sub = (c & 3) * 8;
      GLDS16(A   + (size_t)(m0 + row) * K + k0 + sub,          (char*)As + ldso);
      GLDS16(W1t + (size_t)(n0 + row) * K + k0 + sub,          (char*)Bu + ldso);
      GLDS16(W1t + (size_t)(2048 + n0 + row) * K + k0 + sub,   (char*)Bg + ldso);
    }
    __syncthreads();
    short8v a[4], bu[4], bg[4];
    #pragma unroll
    for (int m = 0; m < 4; m++)
      a[m] = *(const short8v*)((const char*)As + (wr * 64 + m * 16 + r16) * 64 + q4 * 16);
    #pragma unroll
    for (int n = 0; n < 4; n++) {
      bu[n] = *(const short8v*)((const char*)Bu + (wc * 64 + n * 16 + r16) * 64 + q4 * 16);
      bg[n] = *(const short8v*)((const char*)Bg + (wc * 64 + n * 16 + r16) * 64 + q4 * 16);
    }
    #pragma unroll
    for (int m = 0; m < 4; m++)
      #pragma unroll
      for (int n = 0; n < 4; n++) {
        au[m][n] = __builtin_amdgcn_mfma_f32_16x16x32_bf16(a[m], bu[n], au[m][n], 0, 0, 0);
        ag[m][n] = __builtin_amdgcn_mfma_f32_16x16x32_bf16(a[m], bg[n], ag[m][n], 0, 0, 0);
      }
    __syncthreads();
  }
  #pragma unroll
  for (int m = 0; m < 4; m++) {
    int gm0 = m0 + wr * 64 + m * 16 + q4 * 4;
    #pragma unroll
    for (int n = 0; n < 4; n++) {
      int gc = n0 + wc * 64 + n * 16 + r16;
      float bu_ = bias[gc], bg_ = bias[2048 + gc];
      #pragma unroll
      for (int r = 0; r < 4; r++) {
        float u = au[m][n][r] + bu_;
        float g = ag[m][n][r] + bg_;
        float ge = 0.5f * g * (1.f + erff(g * 0.70710678118f));
        out[(size_t)(gm0 + r) * 2048 + gc] = f2b(u * ge);
      }
    }
  }
}

// ======================= Self-attention: MFMA flash (no 1/sqrt(d) scale) ===================
// grid 1024 = B*NH*(S/64). Block: 4 waves; wave w owns q-rows [w*16, w*16+16).
// q,k: (B*S, 512) bf16. vt: (B, 512, S) bf16 (V transposed per channel). o: (B*S,512) bf16.
// LDS tiles 64 rows x 128B, XOR-swizzled via pre-swizzled global source (m173):
//   linear 16B-unit g holds global col-group g^(row&7); reads XOR the same.
__global__ __launch_bounds__(256) void attn_self_mfma(const u16* __restrict__ q,
    const u16* __restrict__ k, const u16* __restrict__ vt, u16* __restrict__ o)
{
  __shared__ __align__(16) u16 Qs[64 * 64];
  __shared__ __align__(16) u16 Ks[2][64 * 64];
  __shared__ __align__(16) u16 Vs[2][64 * 64];
  __shared__ __align__(16) u16 Ps[4 * 16 * 64];
  int tid = threadIdx.x, lane = tid & 63, wid = tid >> 6;
  int r16 = lane & 15, q4 = lane >> 4;
  int qt = blockIdx.x & 15, h = (blockIdx.x >> 4) & 7, b = blockIdx.x >> 7;

  const u16* qg = q  + ((size_t)(b * Sn + qt * 64)) * Cn + h * 64;
  const u16* kg = k  + ((size_t)b * Sn) * Cn + h * 64;
  const u16* vg = vt + ((size_t)(b * Cn + h * 64)) * Sn;

  // stage a 64x64 bf16 tile (row stride rs u16) with inverse-swizzled source
  #define STAGE_T(dst, gbase, rs) do { \
    _Pragma("unroll") \
    for (int ii = 0; ii < 2; ii++) { \
      int rr = ii * 32 + wid * 8 + (lane >> 3); \
      GLDS16((gbase) + (size_t)rr * (rs) + (((lane & 7) ^ (rr & 7)) << 3), \
             (char*)(dst) + ii * 4096 + wid * 1024); \
    } \
  } while (0)

  STAGE_T(Qs, qg, Cn);
  STAGE_T(Ks[0], kg, Cn);
  STAGE_T(Vs[0], vg, Sn);
  __syncthreads();

  // Q fragments (held in registers all kernel)
  short8v aq[2];
  {
    int qrow = wid * 16 + r16, sx = r16 & 7;
    const char* base = (const char*)Qs + qrow * 128;
    aq[0] = *(const short8v*)(base + ((q4 ^ sx) << 4));
    aq[1] = *(const short8v*)(base + (((4 | q4) ^ sx) << 4));
  }

  float m_r[4] = {-1e30f, -1e30f, -1e30f, -1e30f};
  float l_r[4] = {0.f, 0.f, 0.f, 0.f};
  f32x4 acc_o[4] = {};
  int cur = 0;
  char* pwave = (char*)Ps + wid * 2048;

  for (int t = 0; t < 16; t++) {
    if (t < 15) {
      STAGE_T(Ks[cur ^ 1], kg + (size_t)(t + 1) * 64 * Cn, Cn);
      STAGE_T(Vs[cur ^ 1], vg + (t + 1) * 64, Sn);
    }
    // ---- QK^T: 16x64 scores per wave ----
    f32x4 s4[4];
    #pragma unroll
    for (int n = 0; n < 4; n++) {
      int krow = n * 16 + r16, sx = r16 & 7;
      const char* base = (const char*)Ks[cur] + krow * 128;
      short8v b0 = *(const short8v*)(base + ((q4 ^ sx) << 4));
      short8v b1 = *(const short8v*)(base + (((4 | q4) ^ sx) << 4));
      f32x4 z = {0.f, 0.f, 0.f, 0.f};
      z = __builtin_amdgcn_mfma_f32_16x16x32_bf16(aq[0], b0, z, 0, 0, 0);
      s4[n] = __builtin_amdgcn_mfma_f32_16x16x32_bf16(aq[1], b1, z, 0, 0, 0);
    }
    // ---- online softmax (rows live in 16-lane groups; reduce over lane&15) ----
    #pragma unroll
    for (int r = 0; r < 4; r++) {
      float tm = fmaxf(fmaxf(s4[0][r], s4[1][r]), fmaxf(s4[2][r], s4[3][r]));
      #pragma unroll
      for (int off = 8; off; off >>= 1) tm = fmaxf(tm, __shfl_xor(tm, off, 64));
      float mn = fmaxf(m_r[r], tm);
      float al = __expf(m_r[r] - mn);
      m_r[r] = mn;
      int prow = q4 * 4 + r;
      char* pbase = pwave + prow * 128;
      int sx = (prow & 7) << 4;
      float rs = 0.f;
      #pragma unroll
      for (int n = 0; n < 4; n++) {
        float p = __expf(s4[n][r] - mn);
        rs += p;
        int cb = ((((n << 4) | r16) << 1) ^ sx);
        *(u16*)(pbase + cb) = f2b(p);
      }
      #pragma unroll
      for (int off = 8; off; off >>= 1) rs += __shfl_xor(rs, off, 64);
      l_r[r] = l_r[r] * al + rs;
      #pragma unroll
      for (int n = 0; n < 4; n++) acc_o[n][r] *= al;
    }
    __syncthreads();   // P visible wave-wide (and drains next-tile staging early)
    // ---- PV: O += P(16x64) * V(64x64) ----
    short8v pa0, pa1;
    {
      int sx = r16 & 7;
      const char* base = pwave + r16 * 128;
      pa0 = *(const short8v*)(base + ((q4 ^ sx) << 4));
      pa1 = *(const short8v*)(base + (((4 | q4) ^ sx) << 4));
    }
    #pragma unroll
    for (int n = 0; n < 4; n++) {
      int vrow = n * 16 + r16, sx = r16 & 7;
      const char* base = (const char*)Vs[cur] + vrow * 128;
      short8v v0 = *(const short8v*)(base + ((q4 ^ sx) << 4));
      short8v v1 = *(const short8v*)(base + (((4 | q4) ^ sx) << 4));
      acc_o[n] = __builtin_amdgcn_mfma_f32_16x16x32_bf16(pa0, v0, acc_o[n], 0, 0, 0);
      acc_o[n] = __builtin_amdgcn_mfma_f32_16x16x32_bf16(pa1, v1, acc_o[n], 0, 0, 0);
    }
    __syncthreads();   // all waves done with Ks/Vs[cur]; next tile resident
    cur ^= 1;
  }

  // ---- epilogue: O / l, write bf16 ----
  u16* ob = o + ((size_t)(b * Sn + qt * 64 + wid * 16 + q4 * 4)) * Cn + h * 64;
  #pragma unroll
  for (int r = 0; r < 4; r++) {
    float inv = 1.f / l_r[r];
    #pragma unroll
    for (int n = 0; n < 4; n++)
      ob[(size_t)r * Cn + n * 16 + r16] = f2b(acc_o[n][r] * inv);
  }
  #undef STAGE_T
}

// ======================= cross V^T build: (640,512) bf16 -> (B,512,96) bf16, pad j>=77 = 0 =
__global__ __launch_bounds__(256) void vt_cross_k(const u16* __restrict__ v,
    u16* __restrict__ vt)
{
  int c = blockIdx.x * 256 + threadIdx.x;   // 0..511
  int b = blockIdx.y;
  u16* op = vt + ((size_t)b * Cn + c) * 96;
  for (int j = 0; j < 96; j++)
    op[j] = (j < NCn) ? v[((size_t)b * NCn + j) * Cn + c] : (u16)0;
}

// ======================= Cross-attention MFMA (Sk=77 padded to 96, no scale) ===============
// grid 1024 = B*NH*(S/64); 4 waves, wave = 16 q rows. Q,K read direct from global bf16;
// V^T (B,512,96) bf16. Mask cols >= 77. P staged per-wave in LDS (rows padded to 104 u16).
__global__ __launch_bounds__(256) void attn_cross_mfma(const u16* __restrict__ q,
    const u16* __restrict__ k, const u16* __restrict__ vt, u16* __restrict__ o)
{
  __shared__ __align__(16) u16 Ps[4][16 * 104];
  int tid = threadIdx.x, lane = tid & 63, wid = tid >> 6;
  int r16 = lane & 15, q4 = lane >> 4;
  int qt = blockIdx.x & 15, h = (blockIdx.x >> 4) & 7, b = blockIdx.x >> 7;

  // Q fragments (A): row = qt*64 + wid*16 + r16, k-dim = q4*8 .. +8 (and +32)
  const u16* qg = q + ((size_t)(b * Sn + qt * 64 + wid * 16 + r16)) * Cn + h * 64 + q4 * 8;
  short8v aq0 = *(const short8v*)qg;
  short8v aq1 = *(const short8v*)(qg + 32);

  // ---- QK^T: 6 key-groups of 16 (keys 0..95; rows beyond data are masked) ----
  f32x4 s[6];
  #pragma unroll
  for (int n = 0; n < 6; n++) {
    const u16* kr = k + ((size_t)(b * NCn + n * 16 + r16)) * Cn + h * 64 + q4 * 8;
    short8v b0 = *(const short8v*)kr;
    short8v b1 = *(const short8v*)(kr + 32);
    f32x4 z = {0.f, 0.f, 0.f, 0.f};
    z = __builtin_amdgcn_mfma_f32_16x16x32_bf16(aq0, b0, z, 0, 0, 0);
    s[n] = __builtin_amdgcn_mfma_f32_16x16x32_bf16(aq1, b1, z, 0, 0, 0);
  }
  // mask padded keys (this lane's column = n*16 + r16)
  #pragma unroll
  for (int n = 0; n < 6; n++)
    if (n * 16 + r16 >= NCn) {
      s[n][0] = -1e30f; s[n][1] = -1e30f; s[n][2] = -1e30f; s[n][3] = -1e30f;
    }

  // ---- softmax (one shot; rows in 16-lane groups) + P -> LDS ----
  float l_r[4];
  u16* pw = &Ps[wid][0];
  #pragma unroll
  for (int r = 0; r < 4; r++) {
    float tm = -1e30f;
    #pragma unroll
    for (int n = 0; n < 6; n++) tm = fmaxf(tm, s[n][r]);
    #pragma unroll
    for (int off = 8; off; off >>= 1) tm = fmaxf(tm, __shfl_xor(tm, off, 64));
    int prow = q4 * 4 + r;
    float rs = 0.f;
    #pragma unroll
    for (int n = 0; n < 6; n++) {
      float p = __expf(s[n][r] - tm);
      rs += p;
      pw[prow * 104 + n * 16 + r16] = f2b(p);
    }
    #pragma unroll
    for (int off = 8; off; off >>= 1) rs += __shfl_xor(rs, off, 64);
    l_r[r] = rs;
  }
  __syncthreads();

  // ---- PV: O(16x64) = P(16x96) * V(96x64) ----
  short8v pa[3];
  #pragma unroll
  for (int c = 0; c < 3; c++)
    pa[c] = *(const short8v*)(pw + r16 * 104 + c * 32 + q4 * 8);
  f32x4 acc[4] = {};
  #pragma unroll
  for (int n = 0; n < 4; n++) {
    const u16* vr = vt + ((size_t)(b * Cn + h * 64 + n * 16 + r16)) * 96;
    #pragma unroll
    for (int c = 0; c < 3; c++) {
      short8v bv = *(const short8v*)(vr + c * 32 + q4 * 8);
      acc[n] = __builtin_amdgcn_mfma_f32_16x16x32_bf16(pa[c], bv, acc[n], 0, 0, 0);
    }
  }

  // ---- epilogue ----
  u16* ob = o + ((size_t)(b * Sn + qt * 64 + wid * 16 + q4 * 4)) * Cn + h * 64;
  #pragma unroll
  for (int r = 0; r < 4; r++) {
    float inv = 1.f / l_r[r];
    #pragma unroll
    for (int n = 0; n < 4; n++)
      ob[(size_t)r * Cn + n * 16 + r16] = f2b(acc[n][r] * inv);
  }
}

// ======================= Transpose (B,HW,C)->(B,C,HW) + pout_b + x_in ======================
__global__ __launch_bounds__(256) void trans_add(const float* __restrict__ tin,
    const float* __restrict__ pb, const float* __restrict__ xin, float* __restrict__ out)
{
  __shared__ float tile[32][33];
  int p0 = blockIdx.x * 32, d0 = blockIdx.y * 32, b = blockIdx.z;
  int px = threadIdx.x & 31, py = threadIdx.x >> 5;
  for (int yy = py; yy < 32; yy += 8)
    tile[yy][px] = tin[((size_t)b * HWn + p0 + yy) * Cn + d0 + px];
  __syncthreads();
  for (int yy = py; yy < 32; yy += 8) {
    int dd = d0 + yy;
    size_t oidx = ((size_t)b * Cn + dd) * HWn + p0 + px;
    out[oidx] = tile[px][yy] + pb[dd] + xin[oidx];
  }
}

// ======================= Launch ============================================================
extern "C" void kernel_launch(void* const* d_in, const int* in_sizes, int n_in,
                              void* d_out, int out_size, void* d_ws, size_t ws_size,
                              hipStream_t stream) {
  const float* x      = (const float*)d_in[0];
  const float* cond   = (const float*)d_in[1];
  const float* gn_s   = (const float*)d_in[2];
  const float* gn_b   = (const float*)d_in[3];
  const float* pin_w  = (const float*)d_in[4];
  const float* pin_b  = (const float*)d_in[5];
  const float* pout_w = (const float*)d_in[6];
  const float* pout_b = (const float*)d_in[7];
  const float* ln1_s  = (const float*)d_in[8];
  const float* ln1_b  = (const float*)d_in[9];
  const float* sa_wq  = (const float*)d_in[10];
  const float* sa_wk  = (const float*)d_in[11];
  const float* sa_wv  = (const float*)d_in[12];
  const float* sa_wo  = (const float*)d_in[13];
  const float* sa_bo  = (const float*)d_in[14];
  const float* ln2_s  = (const float*)d_in[15];
  const float* ln2_b  = (const float*)d_in[16];
  const float* ca_wq  = (const float*)d_in[17];
  const float* ca_wk  = (const float*)d_in[18];
  const float* ca_wv  = (const float*)d_in[19];
  const float* ca_wo  = (const float*)d_in[20];
  const float* ca_bo  = (const float*)d_in[21];
  const float* ln3_s  = (const float*)d_in[22];
  const float* ln3_b  = (const float*)d_in[23];
  const float* ff_w1  = (const float*)d_in[24];
  const float* ff_b1  = (const float*)d_in[25];
  const float* ff_w2  = (const float*)d_in[26];
  const float* ff_b2  = (const float*)d_in[27];

  const int M = Bn * Sn;  // 8192
  const size_t MB = 1ull << 20;
  char* ws = (char*)d_ws;
  float* t     = (float*)(ws);            // 16 MB  fp32 residual stream
  u16*   abf   = (u16*)  (ws + 16 * MB);  //  8 MB  LN out / attn out (bf16)
  float* qb    = (float*)(ws + 24 * MB);  // 16 MB  (fp32 pout tmp; bf16 q aliases)
  float* kb    = (float*)(ws + 40 * MB);  // 16 MB
  float* vb    = (float*)(ws + 56 * MB);  // 16 MB
  u16*   hb    = (u16*)  (ws + 72 * MB);  // 32 MB  GEGLU out (aliases gnout+xb)
  float* gnout = (float*)(ws + 72 * MB);  // 16 MB  (alias, start only)
  u16*   xb    = (u16*)  (ws + 88 * MB);  //  8 MB  (alias; also tb at end)
  u16*   vtc   = (u16*)  (ws + 96 * MB);  //  0.79 MB cross V^T (B,512,96)
  u16*   condb = (u16*)  (ws + 104 * MB); //  0.95 MB
  u16*   wts   = (u16*)  (ws + 105 * MB); // ~23.1 MB

  u16* q16  = (u16*)qb;   // bf16 Q (self & cross)
  u16* k16  = (u16*)kb;   // bf16 K
  u16* v16  = (u16*)vb;   // bf16 V (cross, row-major) / self V^T aliases below
  u16* vt16 = (u16*)vb;   // self-attn bf16 V^T (B, C, S)

  // weight bf16-transpose pointers
  u16* wp = wts;
  u16* pinT  = wp; wp += 512 * 512;
  u16* poutT = wp; wp += 512 * 512;
  u16 *sa_wqT[2], *sa_wkT[2], *sa_wvT[2], *sa_woT[2];
  u16 *ca_wqT[2], *ca_wkT[2], *ca_wvT[2], *ca_woT[2], *ff_w1T[2], *ff_w2T[2];
  for (int i = 0; i < 2; i++) {
    sa_wqT[i] = wp; wp += 512 * 512;
    sa_wkT[i] = wp; wp += 512 * 512;
    sa_wvT[i] = wp; wp += 512 * 512;
    sa_woT[i] = wp; wp += 512 * 512;
    ca_wqT[i] = wp; wp += 512 * 512;
    ca_wkT[i] = wp; wp += 768 * 512;
    ca_wvT[i] = wp; wp += 768 * 512;
    ca_woT[i] = wp; wp += 512 * 512;
    ff_w1T[i] = wp; wp += 512 * 4096;
    ff_w2T[i] = wp; wp += 2048 * 512;
  }

  // ---- weight casts (transpose to (N,K) bf16) ----
  dim3 tcc(16, 16);
  w_cast_t<<<tcc, 256, 0, stream>>>(pin_w, pinT, 512, 512);
  w_cast_t<<<tcc, 256, 0, stream>>>(pout_w, poutT, 512, 512);
  for (int i = 0; i < 2; i++) {
    const size_t wCC = (size_t)i * 512 * 512, wDC = (size_t)i * 768 * 512;
    w_cast_t<<<tcc, 256, 0, stream>>>(sa_wq + wCC, sa_wqT[i], 512, 512);
    w_cast_t<<<tcc, 256, 0, stream>>>(sa_wk + wCC, sa_wkT[i], 512, 512);
    w_cast_t<<<tcc, 256, 0, stream>>>(sa_wv + wCC, sa_wvT[i], 512, 512);
    w_cast_t<<<tcc, 256, 0, stream>>>(sa_wo + wCC, sa_woT[i], 512, 512);
    w_cast_t<<<tcc, 256, 0, stream>>>(ca_wq + wCC, ca_wqT[i], 512, 512);
    w_cast_t<<<dim3(24, 16), 256, 0, stream>>>(ca_wk + wDC, ca_wkT[i], 768, 512);
    w_cast_t<<<dim3(24, 16), 256, 0, stream>>>(ca_wv + wDC, ca_wvT[i], 768, 512);
    w_cast_t<<<tcc, 256, 0, stream>>>(ca_wo + wCC, ca_woT[i], 512, 512);
    w_cast_t<<<dim3(16, 128), 256, 0, stream>>>(ff_w1 + (size_t)i * 512 * 4096, ff_w1T[i], 512, 4096);
    w_cast_t<<<dim3(64, 16), 256, 0, stream>>>(ff_w2 + (size_t)i * 2048 * 512, ff_w2T[i], 2048, 512);
  }
  cond_cast<<<(NCp * DCn) / 256, 256, 0, stream>>>(cond, condb);

  // ---- GN -> transpose/cast -> proj_in ----
  gn_kernel<<<256, 256, 0, stream>>>(x, gn_s, gn_b, gnout);
  gn_t_cast<<<dim3(32, 16, 8), 256, 0, stream>>>(gnout, xb);
  gemm_mfma<1, 0><<<dim3(4, 64), 256, 0, stream>>>(xb, pinT, pin_b, nullptr, t, M, 512, 512);

  for (int i = 0; i < 2; i++) {
    // --- self-attention (bf16 MFMA flash) ---
    ln_kernel<<<2048, 256, 0, stream>>>(t, ln1_s + i * Cn, ln1_b + i * Cn, abf);
    gemm_mfma<0, 1><<<dim3(4, 64), 256, 0, stream>>>(abf, sa_wqT[i], nullptr, nullptr, q16, M, 512, 512);
    gemm_mfma<0, 1><<<dim3(4, 64), 256, 0, stream>>>(abf, sa_wkT[i], nullptr, nullptr, k16, M, 512, 512);
    gemm_mfma<0, 2><<<dim3(4, 64), 256, 0, stream>>>(abf, sa_wvT[i], nullptr, nullptr, vt16, M, 512, 512);
    attn_self_mfma<<<1024, 256, 0, stream>>>(q16, k16, vt16, abf);
    gemm_mfma<2, 0><<<dim3(4, 64), 256, 0, stream>>>(abf, sa_woT[i], sa_bo + i * Cn, t, t, M, 512, 512);
    // --- cross-attention (bf16 MFMA) ---
    ln_kernel<<<2048, 256, 0, stream>>>(t, ln2_s + i * Cn, ln2_b + i * Cn, abf);
    gemm_mfma<0, 1><<<dim3(4, 64), 256, 0, stream>>>(abf, ca_wqT[i], nullptr, nullptr, q16, M, 512, 512);
    gemm_mfma<0, 1><<<dim3(4, 5), 256, 0, stream>>>(condb, ca_wkT[i], nullptr, nullptr, k16, NCp, 768, 512);
    gemm_mfma<0, 1><<<dim3(4, 5), 256, 0, stream>>>(condb, ca_wvT[i], nullptr, nullptr, v16, NCp, 768, 512);
    vt_cross_k<<<dim3(2, 8), 256, 0, stream>>>(v16, vtc);
    attn_cross_mfma<<<1024, 256, 0, stream>>>(q16, k16, vtc, abf);
    gemm_mfma<2, 0><<<dim3(4, 64), 256, 0, stream>>>(abf, ca_woT[i], ca_bo + i * Cn, t, t, M, 512, 512);
    // --- GEGLU FF ---
    ln_kernel<<<2048, 256, 0, stream>>>(t, ln3_s + i * Cn, ln3_b + i * Cn, abf);
    ff_gate_mfma<<<dim3(16, 64), 256, 0, stream>>>(abf, ff_w1T[i], ff_b1 + i * 4096, hb, M, 512);
    gemm_mfma<2, 0><<<dim3(4, 64), 256, 0, stream>>>(hb, ff_w2T[i], ff_b2 + i * Cn, t, t, M, 2048, 512);
  }

  // ---- proj_out + residual ----
  cast_f2b8<<<2048, 256, 0, stream>>>(t, xb);   // t -> bf16, reuses xb slot
  gemm_mfma<0, 0><<<dim3(4, 64), 256, 0, stream>>>(xb, poutT, nullptr, nullptr, qb, M, 512, 512);
  trans_add<<<dim3(32, 16, 8), 256, 0, stream>>>(qb, pout_b, x, (float*)d_out);
}

// Round 10
// 992.257 us; speedup vs baseline: 4.5354x; 1.1314x over previous
//
#include <hip/hip_runtime.h>
#include <math.h>

static constexpr int Bn  = 8;
static constexpr int Cn  = 512;
static constexpr int HWn = 1024;   // 32*32
static constexpr int Sn  = 1024;   // seq len
static constexpr int NCn = 77;
static constexpr int NCp = 640;    // padded cond rows (8*77=616 -> 640)
static constexpr int DCn = 768;

typedef unsigned short u16;
typedef __attribute__((ext_vector_type(8))) short short8v;   // 8 bf16 (4 VGPRs)
typedef __attribute__((ext_vector_type(4))) float f32x4;
typedef __attribute__((ext_vector_type(8))) unsigned short u16x8;

__device__ __forceinline__ u16 f2b(float f) {
  unsigned u = __float_as_uint(f);
  return (u16)((u + 0x7fffu + ((u >> 16) & 1u)) >> 16);
}
__device__ __forceinline__ float b2f(u16 h) {
  return __uint_as_float(((unsigned)h) << 16);
}
// Abramowitz-Stegun 7.1.26 erf, |err| <= 1.5e-7 (hardware exp)
__device__ __forceinline__ float erf_as(float x) {
  float ax = fabsf(x);
  float t  = 1.f / (1.f + 0.3275911f * ax);
  float y  = t * (0.254829592f + t * (-0.284496736f + t * (1.421413741f +
             t * (-1.453152027f + t * 1.061405429f))));
  float r  = 1.f - y * __expf(-ax * ax);
  return copysignf(r, x);
}

#define GLDS16(gp, lp) __builtin_amdgcn_global_load_lds( \
    (const __attribute__((address_space(1))) void*)(gp),  \
    (__attribute__((address_space(3))) void*)(lp), 16, 0, 0)

// ======================= weight transpose-cast: (K,N) f32 -> (N,K) bf16 ====================
__global__ __launch_bounds__(256) void w_cast_t(const float* __restrict__ in,
    u16* __restrict__ out, int K, int N)
{
  __shared__ float tile[32][33];
  int k0 = blockIdx.x * 32, n0 = blockIdx.y * 32;
  int px = threadIdx.x & 31, py = threadIdx.x >> 5;
  for (int yy = py; yy < 32; yy += 8)
    tile[yy][px] = in[(size_t)(k0 + yy) * N + n0 + px];
  __syncthreads();
  for (int yy = py; yy < 32; yy += 8)
    out[(size_t)(n0 + yy) * K + k0 + px] = f2b(tile[px][yy]);
}

// ======================= cond cast: (616,768) f32 -> (640,768) bf16, pad=0 =================
__global__ __launch_bounds__(256) void cond_cast(const float* __restrict__ in,
    u16* __restrict__ out)
{
  int idx = blockIdx.x * 256 + threadIdx.x;        // 640*768 total
  int m = idx / DCn;
  out[idx] = (m < Bn * NCn) ? f2b(in[idx]) : (u16)0;
}

// ======================= elementwise f32 -> bf16 (vec8) ====================================
__global__ __launch_bounds__(256) void cast_f2b8(const float* __restrict__ in,
    u16* __restrict__ out)
{
  int i = blockIdx.x * 256 + threadIdx.x;          // covers n/8
  const float4* p = (const float4*)(in + (size_t)i * 8);
  float4 a = p[0], b = p[1];
  u16x8 o;
  o[0] = f2b(a.x); o[1] = f2b(a.y); o[2] = f2b(a.z); o[3] = f2b(a.w);
  o[4] = f2b(b.x); o[5] = f2b(b.y); o[6] = f2b(b.z); o[7] = f2b(b.w);
  *(u16x8*)(out + (size_t)i * 8) = o;
}

// ======================= GroupNorm: (B,C,H,W) -> (B,C,HW) normalized fp32 ==================
__global__ __launch_bounds__(256) void gn_kernel(const float* __restrict__ x,
    const float* __restrict__ gs, const float* __restrict__ gb, float* __restrict__ out)
{
  int b = blockIdx.x >> 5, g = blockIdx.x & 31;
  const float* xp = x + ((size_t)b * Cn + g * 16) * HWn;
  float s = 0.f, ss = 0.f;
  for (int e = threadIdx.x; e < 16 * HWn; e += 256) {
    float v = xp[e];
    s += v; ss += v * v;
  }
  __shared__ float red[10];
  #pragma unroll
  for (int o = 32; o; o >>= 1) { s += __shfl_xor(s, o, 64); ss += __shfl_xor(ss, o, 64); }
  if ((threadIdx.x & 63) == 0) { red[threadIdx.x >> 6] = s; red[(threadIdx.x >> 6) + 4] = ss; }
  __syncthreads();
  if (threadIdx.x == 0) {
    float st  = red[0] + red[1] + red[2] + red[3];
    float sst = red[4] + red[5] + red[6] + red[7];
    float mu  = st * (1.f / 16384.f);
    red[8] = mu;
    red[9] = rsqrtf(sst * (1.f / 16384.f) - mu * mu + 1e-6f);
  }
  __syncthreads();
  float mu = red[8], inv = red[9];
  float* op = out + ((size_t)b * Cn + g * 16) * HWn;
  for (int e = threadIdx.x; e < 16 * HWn; e += 256) {
    int cl = e >> 10;
    op[e] = (xp[e] - mu) * inv * gs[g * 16 + cl] + gb[g * 16 + cl];
  }
}

// ======================= (B,C,HW) f32 -> (B*HW, C) bf16 transpose ==========================
__global__ __launch_bounds__(256) void gn_t_cast(const float* __restrict__ in,
    u16* __restrict__ out)
{
  __shared__ float tile[32][33];
  int p0 = blockIdx.x * 32, c0 = blockIdx.y * 32, b = blockIdx.z;
  int px = threadIdx.x & 31, py = threadIdx.x >> 5;
  for (int yy = py; yy < 32; yy += 8)
    tile[yy][px] = in[((size_t)b * Cn + c0 + yy) * HWn + p0 + px];
  __syncthreads();
  for (int yy = py; yy < 32; yy += 8)
    out[((size_t)b * HWn + p0 + yy) * Cn + c0 + px] = f2b(tile[px][yy]);
}

// ======================= LayerNorm (512) f32 in -> bf16 out ================================
__global__ __launch_bounds__(256) void ln_kernel(const float* __restrict__ in,
    const float* __restrict__ s, const float* __restrict__ b, u16* __restrict__ out)
{
  int row  = blockIdx.x * 4 + (threadIdx.x >> 6);
  int lane = threadIdx.x & 63;
  const float* ip = in + (size_t)row * Cn + lane * 8;
  float4 v0 = *(const float4*)ip;
  float4 v1 = *(const float4*)(ip + 4);
  float sum = v0.x + v0.y + v0.z + v0.w + v1.x + v1.y + v1.z + v1.w;
  float ss  = v0.x*v0.x + v0.y*v0.y + v0.z*v0.z + v0.w*v0.w
            + v1.x*v1.x + v1.y*v1.y + v1.z*v1.z + v1.w*v1.w;
  #pragma unroll
  for (int o = 32; o; o >>= 1) { sum += __shfl_xor(sum, o, 64); ss += __shfl_xor(ss, o, 64); }
  float mu  = sum * (1.f / Cn);
  float inv = rsqrtf(ss * (1.f / Cn) - mu * mu + 1e-5f);
  const float4 s0 = *(const float4*)(s + lane * 8);
  const float4 s1 = *(const float4*)(s + lane * 8 + 4);
  const float4 b0 = *(const float4*)(b + lane * 8);
  const float4 b1 = *(const float4*)(b + lane * 8 + 4);
  u16x8 o;
  o[0] = f2b((v0.x - mu) * inv * s0.x + b0.x);
  o[1] = f2b((v0.y - mu) * inv * s0.y + b0.y);
  o[2] = f2b((v0.z - mu) * inv * s0.z + b0.z);
  o[3] = f2b((v0.w - mu) * inv * s0.w + b0.w);
  o[4] = f2b((v1.x - mu) * inv * s1.x + b1.x);
  o[5] = f2b((v1.y - mu) * inv * s1.y + b1.y);
  o[6] = f2b((v1.z - mu) * inv * s1.z + b1.z);
  o[7] = f2b((v1.w - mu) * inv * s1.w + b1.w);
  *(u16x8*)(out + (size_t)row * Cn + lane * 8) = o;
}

// ======================= MFMA GEMM =========================================================
// A (M,K) bf16 row-major; Bt (N,K) bf16 row-major. MTx128 tile (MT=128 or 64), BK=32, 4 waves.
// EPI: 0 none, 1 +bias, 2 +bias+res.
// OUT: 0 f32 row-major (M,N) -> outp
//      1 bf16 row-major (M,N) -> outp
//      2 bf16 V^T (b,c,s), m=b*1024+s -> outp
//      3 QKV split (N=1536): col<512 -> outp bf16 RM(512); <1024 -> out2 bf16 RM; else out3 V^T
//      4 KV split  (N=1024): col<512 -> outp bf16 RM(512); else out2 bf16 RM
template<int EPI, int OUT, int MT>
__global__ __launch_bounds__(256) void gemm_mfma(const u16* __restrict__ A,
    const u16* __restrict__ Bt, const float* __restrict__ bias,
    const float* __restrict__ res, void* __restrict__ outp,
    void* __restrict__ out2, void* __restrict__ out3, int M, int K, int N)
{
  constexpr int MFR = MT / 32;                 // m-frags per wave
  __shared__ __align__(16) u16 As[MT * 32];
  __shared__ __align__(16) u16 Bs[128 * 32];
  int tid = threadIdx.x, lane = tid & 63, wid = tid >> 6;
  int n0 = blockIdx.x * 128, m0 = blockIdx.y * MT;
  int wr = wid >> 1, wc = wid & 1;
  int r16 = lane & 15, q4 = lane >> 4;
  f32x4 acc[MFR][4] = {};
  for (int k0 = 0; k0 < K; k0 += 32) {
    if (MT == 128) {
      #pragma unroll
      for (int i = 0; i < 2; i++) {
        int c = wid * 128 + i * 64 + lane;               // chunk: row=c>>2, sub=c&3
        GLDS16(A + (size_t)(m0 + (c >> 2)) * K + k0 + (c & 3) * 8,
               (char*)As + (size_t)(wid * 2 + i) * 1024);
      }
    } else {
      int c = tid;                                        // 256 chunks = 64 rows
      GLDS16(A + (size_t)(m0 + (c >> 2)) * K + k0 + (c & 3) * 8,
             (char*)As + (size_t)wid * 1024);
    }
    #pragma unroll
    for (int i = 0; i < 2; i++) {
      int c = wid * 128 + i * 64 + lane;
      GLDS16(Bt + (size_t)(n0 + (c >> 2)) * K + k0 + (c & 3) * 8,
             (char*)Bs + (size_t)(wid * 2 + i) * 1024);
    }
    __syncthreads();
    short8v a[MFR], b[4];
    #pragma unroll
    for (int m = 0; m < MFR; m++)
      a[m] = *(const short8v*)((const char*)As + (wr * (MT / 2) + m * 16 + r16) * 64 + q4 * 16);
    #pragma unroll
    for (int n = 0; n < 4; n++)
      b[n] = *(const short8v*)((const char*)Bs + (wc * 64 + n * 16 + r16) * 64 + q4 * 16);
    #pragma unroll
    for (int m = 0; m < MFR; m++)
      #pragma unroll
      for (int n = 0; n < 4; n++)
        acc[m][n] = __builtin_amdgcn_mfma_f32_16x16x32_bf16(a[m], b[n], acc[m][n], 0, 0, 0);
    __syncthreads();
  }
  #pragma unroll
  for (int m = 0; m < MFR; m++) {
    int gm0 = m0 + wr * (MT / 2) + m * 16 + q4 * 4;
    #pragma unroll
    for (int n = 0; n < 4; n++) {
      int gc = n0 + wc * 64 + n * 16 + r16;
      float bv = (EPI >= 1) ? bias[gc] : 0.f;
      if (OUT == 2) {
        int bb = gm0 >> 10, s0 = gm0 & 1023;
        ushort4 pk;
        pk.x = f2b(acc[m][n][0] + bv);
        pk.y = f2b(acc[m][n][1] + bv);
        pk.z = f2b(acc[m][n][2] + bv);
        pk.w = f2b(acc[m][n][3] + bv);
        *(ushort4*)((u16*)outp + ((size_t)bb * Cn + gc) * (size_t)Sn + s0) = pk;
      } else if (OUT == 3) {
        if (gc < 1024) {
          u16* dst = (gc < 512) ? (u16*)outp : (u16*)out2;
          int cc = gc & 511;
          #pragma unroll
          for (int r = 0; r < 4; r++)
            dst[(size_t)(gm0 + r) * Cn + cc] = f2b(acc[m][n][r]);
        } else {
          int bb = gm0 >> 10, s0 = gm0 & 1023, cc = gc - 1024;
          ushort4 pk;
          pk.x = f2b(acc[m][n][0]); pk.y = f2b(acc[m][n][1]);
          pk.z = f2b(acc[m][n][2]); pk.w = f2b(acc[m][n][3]);
          *(ushort4*)((u16*)out3 + ((size_t)bb * Cn + cc) * (size_t)Sn + s0) = pk;
        }
      } else if (OUT == 4) {
        u16* dst = (gc < 512) ? (u16*)outp : (u16*)out2;
        int cc = gc & 511;
        #pragma unroll
        for (int r = 0; r < 4; r++)
          dst[(size_t)(gm0 + r) * Cn + cc] = f2b(acc[m][n][r]);
      } else {
        #pragma unroll
        for (int r = 0; r < 4; r++) {
          float v = acc[m][n][r] + bv;
          size_t oi = (size_t)(gm0 + r) * N + gc;
          if (EPI == 2) v += res[oi];
          if (OUT == 0) ((float*)outp)[oi] = v;
          else          ((u16*)outp)[oi]   = f2b(v);
        }
      }
    }
  }
}

// ======================= Fused GEGLU MFMA GEMM =============================================
// A (M,512) bf16, W1t (4096,512) bf16 (rows 0..2047 = u, 2048..4095 = gate).
// out (M,2048) bf16 = (u+bu) * gelu(g+bg).
__global__ __launch_bounds__(256) void ff_gate_mfma(const u16* __restrict__ A,
    const u16* __restrict__ W1t, const float* __restrict__ bias,
    u16* __restrict__ out, int M, int K)
{
  __shared__ __align__(16) u16 As[128 * 32];
  __shared__ __align__(16) u16 Bu[128 * 32];
  __shared__ __align__(16) u16 Bg[128 * 32];
  int tid = threadIdx.x, lane = tid & 63, wid = tid >> 6;
  int n0 = blockIdx.x * 128, m0 = blockIdx.y * 128;
  int wr = wid >> 1, wc = wid & 1;
  int r16 = lane & 15, q4 = lane >> 4;
  f32x4 au[4][4] = {}, ag[4][4] = {};
  for (int k0 = 0; k0 < K; k0 += 32) {
    #pragma unroll
    for (int i = 0; i < 2; i++) {
      int c = wid * 128 + i * 64 + lane;
      size_t ldso = (size_t)(wid * 2 + i) * 1024;
      int row = c >> 2, sub = (c & 3) * 8;
      GLDS16(A   + (size_t)(m0 + row) * K + k0 + sub,          (char*)As + ldso);
      GLDS16(W1t + (size_t)(n0 + row) * K + k0 + sub,          (char*)Bu + ldso);
      GLDS16(W1t + (size_t)(2048 + n0 + row) * K + k0 + sub,   (char*)Bg + ldso);
    }
    __syncthreads();
    short8v a[4], bu[4], bg[4];
    #pragma unroll
    for (int m = 0; m < 4; m++)
      a[m] = *(const short8v*)((const char*)As + (wr * 64 + m * 16 + r16) * 64 + q4 * 16);
    #pragma unroll
    for (int n = 0; n < 4; n++) {
      bu[n] = *(const short8v*)((const char*)Bu + (wc * 64 + n * 16 + r16) * 64 + q4 * 16);
      bg[n] = *(const short8v*)((const char*)Bg + (wc * 64 + n * 16 + r16) * 64 + q4 * 16);
    }
    #pragma unroll
    for (int m = 0; m < 4; m++)
      #pragma unroll
      for (int n = 0; n < 4; n++) {
        au[m][n] = __builtin_amdgcn_mfma_f32_16x16x32_bf16(a[m], bu[n], au[m][n], 0, 0, 0);
        ag[m][n] = __builtin_amdgcn_mfma_f32_16x16x32_bf16(a[m], bg[n], ag[m][n], 0, 0, 0);
      }
    __syncthreads();
  }
  #pragma unroll
  for (int m = 0; m < 4; m++) {
    int gm0 = m0 + wr * 64 + m * 16 + q4 * 4;
    #pragma unroll
    for (int n = 0; n < 4; n++) {
      int gc = n0 + wc * 64 + n * 16 + r16;
      float bu_ = bias[gc], bg_ = bias[2048 + gc];
      #pragma unroll
      for (int r = 0; r < 4; r++) {
        float u = au[m][n][r] + bu_;
        float g = ag[m][n][r] + bg_;
        float ge = 0.5f * g * (1.f + erf_as(g * 0.70710678118f));
        out[(size_t)(gm0 + r) * 2048 + gc] = f2b(u * ge);
      }
    }
  }
}

// ======================= Self-attention: MFMA flash (no 1/sqrt(d) scale) ===================
__global__ __launch_bounds__(256) void attn_self_mfma(const u16* __restrict__ q,
    const u16* __restrict__ k, const u16* __restrict__ vt, u16* __restrict__ o)
{
  __shared__ __align__(16) u16 Qs[64 * 64];
  __shared__ __align__(16) u16 Ks[2][64 * 64];
  __shared__ __align__(16) u16 Vs[2][64 * 64];
  __shared__ __align__(16) u16 Ps[4 * 16 * 64];
  int tid = threadIdx.x, lane = tid & 63, wid = tid >> 6;
  int r16 = lane & 15, q4 = lane >> 4;
  int qt = blockIdx.x & 15, h = (blockIdx.x >> 4) & 7, b = blockIdx.x >> 7;

  const u16* qg = q  + ((size_t)(b * Sn + qt * 64)) * Cn + h * 64;
  const u16* kg = k  + ((size_t)b * Sn) * Cn + h * 64;
  const u16* vg = vt + ((size_t)(b * Cn + h * 64)) * Sn;

  #define STAGE_T(dst, gbase, rs) do { \
    _Pragma("unroll") \
    for (int ii = 0; ii < 2; ii++) { \
      int rr = ii * 32 + wid * 8 + (lane >> 3); \
      GLDS16((gbase) + (size_t)rr * (rs) + (((lane & 7) ^ (rr & 7)) << 3), \
             (char*)(dst) + ii * 4096 + wid * 1024); \
    } \
  } while (0)

  STAGE_T(Qs, qg, Cn);
  STAGE_T(Ks[0], kg, Cn);
  STAGE_T(Vs[0], vg, Sn);
  __syncthreads();

  short8v aq[2];
  {
    int qrow = wid * 16 + r16, sx = r16 & 7;
    const char* base = (const char*)Qs + qrow * 128;
    aq[0] = *(const short8v*)(base + ((q4 ^ sx) << 4));
    aq[1] = *(const short8v*)(base + (((4 | q4) ^ sx) << 4));
  }

  float m_r[4] = {-1e30f, -1e30f, -1e30f, -1e30f};
  float l_r[4] = {0.f, 0.f, 0.f, 0.f};
  f32x4 acc_o[4] = {};
  int cur = 0;
  char* pwave = (char*)Ps + wid * 2048;

  for (int t = 0; t < 16; t++) {
    if (t < 15) {
      STAGE_T(Ks[cur ^ 1], kg + (size_t)(t + 1) * 64 * Cn, Cn);
      STAGE_T(Vs[cur ^ 1], vg + (t + 1) * 64, Sn);
    }
    f32x4 s4[4];
    #pragma unroll
    for (int n = 0; n < 4; n++) {
      int krow = n * 16 + r16, sx = r16 & 7;
      const char* base = (const char*)Ks[cur] + krow * 128;
      short8v b0 = *(const short8v*)(base + ((q4 ^ sx) << 4));
      short8v b1 = *(const short8v*)(base + (((4 | q4) ^ sx) << 4));
      f32x4 z = {0.f, 0.f, 0.f, 0.f};
      z = __builtin_amdgcn_mfma_f32_16x16x32_bf16(aq[0], b0, z, 0, 0, 0);
      s4[n] = __builtin_amdgcn_mfma_f32_16x16x32_bf16(aq[1], b1, z, 0, 0, 0);
    }
    #pragma unroll
    for (int r = 0; r < 4; r++) {
      float tm = fmaxf(fmaxf(s4[0][r], s4[1][r]), fmaxf(s4[2][r], s4[3][r]));
      #pragma unroll
      for (int off = 8; off; off >>= 1) tm = fmaxf(tm, __shfl_xor(tm, off, 64));
      float mn = fmaxf(m_r[r], tm);
      float al = __expf(m_r[r] - mn);
      m_r[r] = mn;
      int prow = q4 * 4 + r;
      char* pbase = pwave + prow * 128;
      int sx = (prow & 7) << 4;
      float rs = 0.f;
      #pragma unroll
      for (int n = 0; n < 4; n++) {
        float p = __expf(s4[n][r] - mn);
        rs += p;
        int cb = ((((n << 4) | r16) << 1) ^ sx);
        *(u16*)(pbase + cb) = f2b(p);
      }
      #pragma unroll
      for (int off = 8; off; off >>= 1) rs += __shfl_xor(rs, off, 64);
      l_r[r] = l_r[r] * al + rs;
      #pragma unroll
      for (int n = 0; n < 4; n++) acc_o[n][r] *= al;
    }
    __syncthreads();
    short8v pa0, pa1;
    {
      int sx = r16 & 7;
      const char* base = pwave + r16 * 128;
      pa0 = *(const short8v*)(base + ((q4 ^ sx) << 4));
      pa1 = *(const short8v*)(base + (((4 | q4) ^ sx) << 4));
    }
    #pragma unroll
    for (int n = 0; n < 4; n++) {
      int vrow = n * 16 + r16, sx = r16 & 7;
      const char* base = (const char*)Vs[cur] + vrow * 128;
      short8v v0 = *(const short8v*)(base + ((q4 ^ sx) << 4));
      short8v v1 = *(const short8v*)(base + (((4 | q4) ^ sx) << 4));
      acc_o[n] = __builtin_amdgcn_mfma_f32_16x16x32_bf16(pa0, v0, acc_o[n], 0, 0, 0);
      acc_o[n] = __builtin_amdgcn_mfma_f32_16x16x32_bf16(pa1, v1, acc_o[n], 0, 0, 0);
    }
    __syncthreads();
    cur ^= 1;
  }

  u16* ob = o + ((size_t)(b * Sn + qt * 64 + wid * 16 + q4 * 4)) * Cn + h * 64;
  #pragma unroll
  for (int r = 0; r < 4; r++) {
    float inv = 1.f / l_r[r];
    #pragma unroll
    for (int n = 0; n < 4; n++)
      ob[(size_t)r * Cn + n * 16 + r16] = f2b(acc_o[n][r] * inv);
  }
  #undef STAGE_T
}

// ======================= cross V^T build: (640,512) bf16 -> (B,512,96) bf16, pad j>=77 = 0 =
__global__ __launch_bounds__(256) void vt_cross_k(const u16* __restrict__ v,
    u16* __restrict__ vt)
{
  int c = blockIdx.x * 256 + threadIdx.x;   // 0..511
  int b = blockIdx.y;
  u16* op = vt + ((size_t)b * Cn + c) * 96;
  for (int j = 0; j < 96; j++)
    op[j] = (j < NCn) ? v[((size_t)b * NCn + j) * Cn + c] : (u16)0;
}

// ======================= Cross-attention MFMA (Sk=77 padded to 96, no scale) ===============
__global__ __launch_bounds__(256) void attn_cross_mfma(const u16* __restrict__ q,
    const u16* __restrict__ k, const u16* __restrict__ vt, u16* __restrict__ o)
{
  __shared__ __align__(16) u16 Ps[4][16 * 104];
  int tid = threadIdx.x, lane = tid & 63, wid = tid >> 6;
  int r16 = lane & 15, q4 = lane >> 4;
  int qt = blockIdx.x & 15, h = (blockIdx.x >> 4) & 7, b = blockIdx.x >> 7;

  const u16* qg = q + ((size_t)(b * Sn + qt * 64 + wid * 16 + r16)) * Cn + h * 64 + q4 * 8;
  short8v aq0 = *(const short8v*)qg;
  short8v aq1 = *(const short8v*)(qg + 32);

  f32x4 s[6];
  #pragma unroll
  for (int n = 0; n < 6; n++) {
    const u16* kr = k + ((size_t)(b * NCn + n * 16 + r16)) * Cn + h * 64 + q4 * 8;
    short8v b0 = *(const short8v*)kr;
    short8v b1 = *(const short8v*)(kr + 32);
    f32x4 z = {0.f, 0.f, 0.f, 0.f};
    z = __builtin_amdgcn_mfma_f32_16x16x32_bf16(aq0, b0, z, 0, 0, 0);
    s[n] = __builtin_amdgcn_mfma_f32_16x16x32_bf16(aq1, b1, z, 0, 0, 0);
  }
  #pragma unroll
  for (int n = 0; n < 6; n++)
    if (n * 16 + r16 >= NCn) {
      s[n][0] = -1e30f; s[n][1] = -1e30f; s[n][2] = -1e30f; s[n][3] = -1e30f;
    }

  float l_r[4];
  u16* pw = &Ps[wid][0];
  #pragma unroll
  for (int r = 0; r < 4; r++) {
    float tm = -1e30f;
    #pragma unroll
    for (int n = 0; n < 6; n++) tm = fmaxf(tm, s[n][r]);
    #pragma unroll
    for (int off = 8; off; off >>= 1) tm = fmaxf(tm, __shfl_xor(tm, off, 64));
    int prow = q4 * 4 + r;
    float rs = 0.f;
    #pragma unroll
    for (int n = 0; n < 6; n++) {
      float p = __expf(s[n][r] - tm);
      rs += p;
      pw[prow * 104 + n * 16 + r16] = f2b(p);
    }
    #pragma unroll
    for (int off = 8; off; off >>= 1) rs += __shfl_xor(rs, off, 64);
    l_r[r] = rs;
  }
  __syncthreads();

  short8v pa[3];
  #pragma unroll
  for (int c = 0; c < 3; c++)
    pa[c] = *(const short8v*)(pw + r16 * 104 + c * 32 + q4 * 8);
  f32x4 acc[4] = {};
  #pragma unroll
  for (int n = 0; n < 4; n++) {
    const u16* vr = vt + ((size_t)(b * Cn + h * 64 + n * 16 + r16)) * 96;
    #pragma unroll
    for (int c = 0; c < 3; c++) {
      short8v bv = *(const short8v*)(vr + c * 32 + q4 * 8);
      acc[n] = __builtin_amdgcn_mfma_f32_16x16x32_bf16(pa[c], bv, acc[n], 0, 0, 0);
    }
  }

  u16* ob = o + ((size_t)(b * Sn + qt * 64 + wid * 16 + q4 * 4)) * Cn + h * 64;
  #pragma unroll
  for (int r = 0; r < 4; r++) {
    float inv = 1.f / l_r[r];
    #pragma unroll
    for (int n = 0; n < 4; n++)
      ob[(size_t)r * Cn + n * 16 + r16] = f2b(acc[n][r] * inv);
  }
}

// ======================= Transpose (B,HW,C)->(B,C,HW) + pout_b + x_in ======================
__global__ __launch_bounds__(256) void trans_add(const float* __restrict__ tin,
    const float* __restrict__ pb, const float* __restrict__ xin, float* __restrict__ out)
{
  __shared__ float tile[32][33];
  int p0 = blockIdx.x * 32, d0 = blockIdx.y * 32, b = blockIdx.z;
  int px = threadIdx.x & 31, py = threadIdx.x >> 5;
  for (int yy = py; yy < 32; yy += 8)
    tile[yy][px] = tin[((size_t)b * HWn + p0 + yy) * Cn + d0 + px];
  __syncthreads();
  for (int yy = py; yy < 32; yy += 8) {
    int dd = d0 + yy;
    size_t oidx = ((size_t)b * Cn + dd) * HWn + p0 + px;
    out[oidx] = tile[px][yy] + pb[dd] + xin[oidx];
  }
}

// ======================= Launch ============================================================
extern "C" void kernel_launch(void* const* d_in, const int* in_sizes, int n_in,
                              void* d_out, int out_size, void* d_ws, size_t ws_size,
                              hipStream_t stream) {
  const float* x      = (const float*)d_in[0];
  const float* cond   = (const float*)d_in[1];
  const float* gn_s   = (const float*)d_in[2];
  const float* gn_b   = (const float*)d_in[3];
  const float* pin_w  = (const float*)d_in[4];
  const float* pin_b  = (const float*)d_in[5];
  const float* pout_w = (const float*)d_in[6];
  const float* pout_b = (const float*)d_in[7];
  const float* ln1_s  = (const float*)d_in[8];
  const float* ln1_b  = (const float*)d_in[9];
  const float* sa_wq  = (const float*)d_in[10];
  const float* sa_wk  = (const float*)d_in[11];
  const float* sa_wv  = (const float*)d_in[12];
  const float* sa_wo  = (const float*)d_in[13];
  const float* sa_bo  = (const float*)d_in[14];
  const float* ln2_s  = (const float*)d_in[15];
  const float* ln2_b  = (const float*)d_in[16];
  const float* ca_wq  = (const float*)d_in[17];
  const float* ca_wk  = (const float*)d_in[18];
  const float* ca_wv  = (const float*)d_in[19];
  const float* ca_wo  = (const float*)d_in[20];
  const float* ca_bo  = (const float*)d_in[21];
  const float* ln3_s  = (const float*)d_in[22];
  const float* ln3_b  = (const float*)d_in[23];
  const float* ff_w1  = (const float*)d_in[24];
  const float* ff_b1  = (const float*)d_in[25];
  const float* ff_w2  = (const float*)d_in[26];
  const float* ff_b2  = (const float*)d_in[27];

  const int M = Bn * Sn;  // 8192
  const size_t MB = 1ull << 20;
  char* ws = (char*)d_ws;
  float* t     = (float*)(ws);            // 16 MB  fp32 residual stream
  u16*   abf   = (u16*)  (ws + 16 * MB);  //  8 MB  LN out / attn out (bf16)
  float* qb    = (float*)(ws + 24 * MB);  // 16 MB  (fp32 pout tmp; bf16 q aliases)
  float* kb    = (float*)(ws + 40 * MB);  // 16 MB
  float* vb    = (float*)(ws + 56 * MB);  // 16 MB
  u16*   hb    = (u16*)  (ws + 72 * MB);  // 32 MB  GEGLU out (aliases gnout+xb)
  float* gnout = (float*)(ws + 72 * MB);  // 16 MB  (alias, start only)
  u16*   xb    = (u16*)  (ws + 88 * MB);  //  8 MB  (alias; also tb at end)
  u16*   vtc   = (u16*)  (ws + 96 * MB);  //  0.79 MB cross V^T (B,512,96)
  u16*   condb = (u16*)  (ws + 104 * MB); //  0.95 MB
  u16*   wts   = (u16*)  (ws + 105 * MB); // ~23.1 MB

  u16* q16  = (u16*)qb;   // bf16 Q (self & cross)
  u16* k16  = (u16*)kb;   // bf16 K
  u16* v16  = (u16*)vb;   // bf16 V (cross row-major); self V^T aliases
  u16* vt16 = (u16*)vb;   // self-attn bf16 V^T (B, C, S)

  // weight bf16-transpose pointers (wq,wk,wv consecutive => fused QKV panel;
  // ca_wk,ca_wv consecutive => fused KV panel)
  u16* wp = wts;
  u16* pinT  = wp; wp += 512 * 512;
  u16* poutT = wp; wp += 512 * 512;
  u16 *sa_wqT[2], *sa_wkT[2], *sa_wvT[2], *sa_woT[2];
  u16 *ca_wqT[2], *ca_wkT[2], *ca_wvT[2], *ca_woT[2], *ff_w1T[2], *ff_w2T[2];
  for (int i = 0; i < 2; i++) {
    sa_wqT[i] = wp; wp += 512 * 512;
    sa_wkT[i] = wp; wp += 512 * 512;
    sa_wvT[i] = wp; wp += 512 * 512;
    sa_woT[i] = wp; wp += 512 * 512;
    ca_wqT[i] = wp; wp += 512 * 512;
    ca_wkT[i] = wp; wp += 768 * 512;
    ca_wvT[i] = wp; wp += 768 * 512;
    ca_woT[i] = wp; wp += 512 * 512;
    ff_w1T[i] = wp; wp += 512 * 4096;
    ff_w2T[i] = wp; wp += 2048 * 512;
  }

  // ---- weight casts (transpose to (N,K) bf16) ----
  dim3 tcc(16, 16);
  w_cast_t<<<tcc, 256, 0, stream>>>(pin_w, pinT, 512, 512);
  w_cast_t<<<tcc, 256, 0, stream>>>(pout_w, poutT, 512, 512);
  for (int i = 0; i < 2; i++) {
    const size_t wCC = (size_t)i * 512 * 512, wDC = (size_t)i * 768 * 512;
    w_cast_t<<<tcc, 256, 0, stream>>>(sa_wq + wCC, sa_wqT[i], 512, 512);
    w_cast_t<<<tcc, 256, 0, stream>>>(sa_wk + wCC, sa_wkT[i], 512, 512);
    w_cast_t<<<tcc, 256, 0, stream>>>(sa_wv + wCC, sa_wvT[i], 512, 512);
    w_cast_t<<<tcc, 256, 0, stream>>>(sa_wo + wCC, sa_woT[i], 512, 512);
    w_cast_t<<<tcc, 256, 0, stream>>>(ca_wq + wCC, ca_wqT[i], 512, 512);
    w_cast_t<<<dim3(24, 16), 256, 0, stream>>>(ca_wk + wDC, ca_wkT[i], 768, 512);
    w_cast_t<<<dim3(24, 16), 256, 0, stream>>>(ca_wv + wDC, ca_wvT[i], 768, 512);
    w_cast_t<<<tcc, 256, 0, stream>>>(ca_wo + wCC, ca_woT[i], 512, 512);
    w_cast_t<<<dim3(16, 128), 256, 0, stream>>>(ff_w1 + (size_t)i * 512 * 4096, ff_w1T[i], 512, 4096);
    w_cast_t<<<dim3(64, 16), 256, 0, stream>>>(ff_w2 + (size_t)i * 2048 * 512, ff_w2T[i], 2048, 512);
  }
  cond_cast<<<(NCp * DCn) / 256, 256, 0, stream>>>(cond, condb);

  // ---- GN -> transpose/cast -> proj_in ----
  gn_kernel<<<256, 256, 0, stream>>>(x, gn_s, gn_b, gnout);
  gn_t_cast<<<dim3(32, 16, 8), 256, 0, stream>>>(gnout, xb);
  gemm_mfma<1, 0, 64><<<dim3(4, 128), 256, 0, stream>>>(xb, pinT, pin_b, nullptr, t, nullptr, nullptr, M, 512, 512);

  for (int i = 0; i < 2; i++) {
    // --- self-attention (bf16 MFMA flash; fused QKV projection) ---
    ln_kernel<<<2048, 256, 0, stream>>>(t, ln1_s + i * Cn, ln1_b + i * Cn, abf);
    gemm_mfma<0, 3, 128><<<dim3(12, 64), 256, 0, stream>>>(abf, sa_wqT[i], nullptr, nullptr, q16, k16, vt16, M, 512, 1536);
    attn_self_mfma<<<1024, 256, 0, stream>>>(q16, k16, vt16, abf);
    gemm_mfma<2, 0, 64><<<dim3(4, 128), 256, 0, stream>>>(abf, sa_woT[i], sa_bo + i * Cn, t, t, nullptr, nullptr, M, 512, 512);
    // --- cross-attention (bf16 MFMA; fused KV projection) ---
    ln_kernel<<<2048, 256, 0, stream>>>(t, ln2_s + i * Cn, ln2_b + i * Cn, abf);
    gemm_mfma<0, 1, 64><<<dim3(4, 128), 256, 0, stream>>>(abf, ca_wqT[i], nullptr, nullptr, q16, nullptr, nullptr, M, 512, 512);
    gemm_mfma<0, 4, 128><<<dim3(8, 5), 256, 0, stream>>>(condb, ca_wkT[i], nullptr, nullptr, k16, v16, nullptr, NCp, 768, 1024);
    vt_cross_k<<<dim3(2, 8), 256, 0, stream>>>(v16, vtc);
    attn_cross_mfma<<<1024, 256, 0, stream>>>(q16, k16, vtc, abf);
    gemm_mfma<2, 0, 64><<<dim3(4, 128), 256, 0, stream>>>(abf, ca_woT[i], ca_bo + i * Cn, t, t, nullptr, nullptr, M, 512, 512);
    // --- GEGLU FF ---
    ln_kernel<<<2048, 256, 0, stream>>>(t, ln3_s + i * Cn, ln3_b + i * Cn, abf);
    ff_gate_mfma<<<dim3(16, 64), 256, 0, stream>>>(abf, ff_w1T[i], ff_b1 + i * 4096, hb, M, 512);
    gemm_mfma<2, 0, 64><<<dim3(4, 128), 256, 0, stream>>>(hb, ff_w2T[i], ff_b2 + i * Cn, t, t, nullptr, nullptr, M, 2048, 512);
  }

  // ---- proj_out + residual ----
  cast_f2b8<<<2048, 256, 0, stream>>>(t, xb);   // t -> bf16, reuses xb slot
  gemm_mfma<0, 0, 64><<<dim3(4, 128), 256, 0, stream>>>(xb, poutT, nullptr, nullptr, qb, nullptr, nullptr, M, 512, 512);
  trans_add<<<dim3(32, 16, 8), 256, 0, stream>>>(qb, pout_b, x, (float*)d_out);
}